// Round 2
// baseline (1757.587 us; speedup 1.0000x reference)
//
#include <hip/hip_runtime.h>
#include <hip/hip_bf16.h>
#include <cstdint>
#include <cstddef>

#define IN_D 256
#define HID 128
#define OUT_D 64
#define NSLOPE 0.2f

static inline int cdiv(long long a, long long b) { return (int)((a + b - 1) / b); }

// Ordered-uint encoding for float atomicMax (total order matches float order)
__device__ __forceinline__ unsigned fenc(float f) {
  unsigned u = __float_as_uint(f);
  return (u & 0x80000000u) ? ~u : (u | 0x80000000u);
}
__device__ __forceinline__ float fdec(unsigned u) {
  return __uint_as_float((u & 0x80000000u) ? (u ^ 0x80000000u) : ~u);
}
#define MENC_INIT 0x00800000u  // enc(-FLT_MAX)

// Edge i -> (src, dst); harness delivers edge_index as int32, layout [2, E].
// Self-loops appended logically for i >= E.
__device__ __forceinline__ void edge_sd(const int* __restrict__ ei, int E, int i,
                                        int& s, int& d) {
  if (i < E) { s = ei[i]; d = ei[E + i]; }
  else       { s = i - E; d = s; }
}

__global__ void k_init(unsigned* m1, float* dn1, unsigned* m2, float* dn2, int N) {
  int i = blockIdx.x * blockDim.x + threadIdx.x;
  if (i < 2 * N) { m1[i] = MENC_INIT; dn1[i] = 0.f; }
  if (i < N)     { m2[i] = MENC_INIT; dn2[i] = 0.f; }
}

// h1 = x @ W1  (N x 256) @ (256 x 256); 8 rows per block, 256 threads = 1 col each
__launch_bounds__(256)
__global__ void k_gemm1(const float* __restrict__ x, const float* __restrict__ W,
                        float* __restrict__ h, int N) {
  __shared__ float xs[8][IN_D];
  int tid = threadIdx.x;
  int row0 = blockIdx.x * 8;
  #pragma unroll
  for (int r = 0; r < 8; ++r) {
    int n = row0 + r;
    xs[r][tid] = (n < N) ? x[(size_t)n * IN_D + tid] : 0.f;
  }
  __syncthreads();
  float acc[8] = {};
  for (int k = 0; k < IN_D; ++k) {
    float w = W[(size_t)k * IN_D + tid];
    #pragma unroll
    for (int r = 0; r < 8; ++r) acc[r] += xs[r][k] * w;
  }
  #pragma unroll
  for (int r = 0; r < 8; ++r) {
    int n = row0 + r;
    if (n < N) h[(size_t)n * IN_D + tid] = acc[r];
  }
}

// a_s1[n,hd] = dot(h1[n,hd,:], att_src1[hd,:]); one wave per (n, head)
__global__ void k_logits1(const float* __restrict__ h, const float* __restrict__ as,
                          const float* __restrict__ ad, float* __restrict__ a_s,
                          float* __restrict__ a_d, int N) {
  int gid = blockIdx.x * blockDim.x + threadIdx.x;
  int wave = gid >> 6, lane = gid & 63;
  int n = wave >> 1, hd = wave & 1;
  if (n >= N) return;
  const float* hp = h + (size_t)n * IN_D + hd * HID;
  const float* asp = as + hd * HID;
  const float* adp = ad + hd * HID;
  float ps = hp[lane] * asp[lane] + hp[lane + 64] * asp[lane + 64];
  float pd = hp[lane] * adp[lane] + hp[lane + 64] * adp[lane + 64];
  #pragma unroll
  for (int o = 32; o; o >>= 1) { ps += __shfl_xor(ps, o); pd += __shfl_xor(pd, o); }
  if (lane == 0) { a_s[n * 2 + hd] = ps; a_d[n * 2 + hd] = pd; }
}

// e = leaky_relu(a_s[src]+a_d[dst]); atomicMax into m[dst]   (2 threads per edge)
__global__ void k_score1(const int* __restrict__ ei, int E, int ET,
                         const float* __restrict__ a_s, const float* __restrict__ a_d,
                         float* __restrict__ e, unsigned* __restrict__ menc) {
  int gid = blockIdx.x * blockDim.x + threadIdx.x;
  if (gid >= 2 * ET) return;
  int i = gid >> 1, hd = gid & 1;
  int s, d; edge_sd(ei, E, i, s, d);
  float v = a_s[s * 2 + hd] + a_d[d * 2 + hd];
  v = (v >= 0.f) ? v : NSLOPE * v;
  e[gid] = v;
  atomicMax(&menc[d * 2 + hd], fenc(v));
}

// w = exp(e - m[dst]); denom[dst] += w
__global__ void k_soft1(const int* __restrict__ ei, int E, int ET,
                        float* __restrict__ e, const unsigned* __restrict__ menc,
                        float* __restrict__ denom) {
  int gid = blockIdx.x * blockDim.x + threadIdx.x;
  if (gid >= 2 * ET) return;
  int i = gid >> 1, hd = gid & 1;
  int s, d; edge_sd(ei, E, i, s, d);
  float m = fdec(menc[d * 2 + hd]);
  float w = __expf(e[gid] - m);
  e[gid] = w;
  atomicAdd(&denom[d * 2 + hd], w);
}

// aggm[dst,c] += 0.5*(al0*h[src,0,c] + al1*h[src,1,c]); head-mean fused.
// One wave per edge, 2 channels per lane.
__launch_bounds__(256)
__global__ void k_agg1(const int* __restrict__ ei, int E, int ET,
                       const float* __restrict__ e, const float* __restrict__ denom,
                       const float* __restrict__ h, float* __restrict__ aggm) {
  int gid = blockIdx.x * blockDim.x + threadIdx.x;
  int i = gid >> 6, lane = gid & 63;
  if (i >= ET) return;
  int s, d; edge_sd(ei, E, i, s, d);
  float al0 = 0.5f * e[(size_t)i * 2]     / denom[d * 2];
  float al1 = 0.5f * e[(size_t)i * 2 + 1] / denom[d * 2 + 1];
  const float* hp = h + (size_t)s * IN_D;
  float* ap = aggm + (size_t)d * HID;
  #pragma unroll
  for (int q = 0; q < 2; ++q) {
    int c = lane + q * 64;
    atomicAdd(&ap[c], al0 * hp[c] + al1 * hp[c + HID]);
  }
}

// h2 = relu(aggm + b1) @ W2 ; 16 rows/block, 64 cols x 4 row-slots
__launch_bounds__(256)
__global__ void k_gemm2(const float* __restrict__ aggm, const float* __restrict__ b1,
                        const float* __restrict__ W2, float* __restrict__ h2, int N) {
  __shared__ float xs[16][HID];
  int tid = threadIdx.x;
  int row0 = blockIdx.x * 16;
  for (int t = tid; t < 16 * HID; t += 256) {
    int r = t >> 7, k = t & 127;
    int n = row0 + r;
    float v = 0.f;
    if (n < N) {
      v = aggm[(size_t)n * HID + k] + b1[k];
      v = (v > 0.f) ? v : 0.f;
    }
    xs[r][k] = v;
  }
  __syncthreads();
  int c = tid & 63, rs = tid >> 6;
  float acc[4] = {};
  for (int k = 0; k < HID; ++k) {
    float w = W2[(size_t)k * OUT_D + c];
    #pragma unroll
    for (int q = 0; q < 4; ++q) acc[q] += xs[rs + q * 4][k] * w;
  }
  #pragma unroll
  for (int q = 0; q < 4; ++q) {
    int n = row0 + rs + q * 4;
    if (n < N) h2[(size_t)n * OUT_D + c] = acc[q];
  }
}

// one wave per node, 64 dims
__global__ void k_logits2(const float* __restrict__ h2, const float* __restrict__ as2,
                          const float* __restrict__ ad2, float* __restrict__ a_s,
                          float* __restrict__ a_d, int N) {
  int gid = blockIdx.x * blockDim.x + threadIdx.x;
  int n = gid >> 6, lane = gid & 63;
  if (n >= N) return;
  float hv = h2[(size_t)n * OUT_D + lane];
  float ps = hv * as2[lane], pd = hv * ad2[lane];
  #pragma unroll
  for (int o = 32; o; o >>= 1) { ps += __shfl_xor(ps, o); pd += __shfl_xor(pd, o); }
  if (lane == 0) { a_s[n] = ps; a_d[n] = pd; }
}

__global__ void k_score2(const int* __restrict__ ei, int E, int ET,
                         const float* __restrict__ a_s, const float* __restrict__ a_d,
                         float* __restrict__ e, unsigned* __restrict__ menc) {
  int i = blockIdx.x * blockDim.x + threadIdx.x;
  if (i >= ET) return;
  int s, d; edge_sd(ei, E, i, s, d);
  float v = a_s[s] + a_d[d];
  v = (v >= 0.f) ? v : NSLOPE * v;
  e[i] = v;
  atomicMax(&menc[d], fenc(v));
}

__global__ void k_soft2(const int* __restrict__ ei, int E, int ET,
                        float* __restrict__ e, const unsigned* __restrict__ menc,
                        float* __restrict__ denom) {
  int i = blockIdx.x * blockDim.x + threadIdx.x;
  if (i >= ET) return;
  int s, d; edge_sd(ei, E, i, s, d);
  float m = fdec(menc[d]);
  float w = __expf(e[i] - m);
  e[i] = w;
  atomicAdd(&denom[d], w);
}

// agg2[dst] += alpha * h2[src]; one wave per edge, 1 elem/lane
__launch_bounds__(256)
__global__ void k_agg2(const int* __restrict__ ei, int E, int ET,
                       const float* __restrict__ e, const float* __restrict__ denom,
                       const float* __restrict__ h2, float* __restrict__ agg) {
  int gid = blockIdx.x * blockDim.x + threadIdx.x;
  int i = gid >> 6, lane = gid & 63;
  if (i >= ET) return;
  int s, d; edge_sd(ei, E, i, s, d);
  float al = e[i] / denom[d];
  atomicAdd(&agg[(size_t)d * OUT_D + lane], al * h2[(size_t)s * OUT_D + lane]);
}

__global__ void k_final(const float* __restrict__ agg2, const float* __restrict__ b2,
                        float* __restrict__ out, long long total) {
  long long gid = (long long)blockIdx.x * blockDim.x + threadIdx.x;
  if (gid >= total) return;
  out[gid] = agg2[gid] + b2[gid & 63];
}

extern "C" void kernel_launch(void* const* d_in, const int* in_sizes, int n_in,
                              void* d_out, int out_size, void* d_ws, size_t ws_size,
                              hipStream_t stream) {
  const float* x    = (const float*)d_in[0];
  const int*   ei   = (const int*)d_in[1];    // harness converts int64 -> int32
  const float* W1   = (const float*)d_in[2];
  const float* as1w = (const float*)d_in[3];
  const float* ad1w = (const float*)d_in[4];
  const float* b1   = (const float*)d_in[5];
  const float* W2   = (const float*)d_in[6];
  const float* as2w = (const float*)d_in[7];
  const float* ad2w = (const float*)d_in[8];
  const float* b2   = (const float*)d_in[9];
  float* out = (float*)d_out;

  const int N  = in_sizes[0] / IN_D;
  const int E  = in_sizes[1] / 2;
  const int ET = E + N;

  // Workspace layout (element offsets; all 4-byte types). Total ~172 MB.
  float* ws = (float*)d_ws;
  size_t off = 0;
  float*    h1   = ws + off; off += (size_t)N * IN_D;   // N*256; h2 & agg2 alias in here
  float*    aggm = ws + off; off += (size_t)N * HID;    // N*128 head-mean aggregate
  float*    e1   = ws + off; off += (size_t)ET * 2;     // e2 aliases e1
  float*    a_s1 = ws + off; off += (size_t)N * 2;
  float*    a_d1 = ws + off; off += (size_t)N * 2;
  float*    a_s2 = ws + off; off += N;
  float*    a_d2 = ws + off; off += N;
  unsigned* m1   = (unsigned*)(ws + off); off += (size_t)N * 2;
  float*    dn1  = ws + off; off += (size_t)N * 2;
  unsigned* m2   = (unsigned*)(ws + off); off += N;
  float*    dn2  = ws + off; off += N;

  float* h2   = h1;                     // h1 dead after k_agg1
  float* agg2 = h1 + (size_t)N * OUT_D; // disjoint from h2's N*64 region
  float* e2   = e1;                     // layer-1 e dead after k_agg1

  k_init<<<cdiv(2LL * N, 256), 256, 0, stream>>>(m1, dn1, m2, dn2, N);
  hipMemsetAsync(aggm, 0, (size_t)N * HID * sizeof(float), stream);

  // Layer 1
  k_gemm1<<<cdiv(N, 8), 256, 0, stream>>>(x, W1, h1, N);
  k_logits1<<<cdiv(2LL * N * 64, 256), 256, 0, stream>>>(h1, as1w, ad1w, a_s1, a_d1, N);
  k_score1<<<cdiv(2LL * ET, 256), 256, 0, stream>>>(ei, E, ET, a_s1, a_d1, e1, m1);
  k_soft1<<<cdiv(2LL * ET, 256), 256, 0, stream>>>(ei, E, ET, e1, m1, dn1);
  k_agg1<<<cdiv((long long)ET * 64, 256), 256, 0, stream>>>(ei, E, ET, e1, dn1, h1, aggm);

  // Layer 2 (gemm2 fuses bias + relu on its load path; head-mean already fused)
  k_gemm2<<<cdiv(N, 16), 256, 0, stream>>>(aggm, b1, W2, h2, N);
  hipMemsetAsync(agg2, 0, (size_t)N * OUT_D * sizeof(float), stream);
  k_logits2<<<cdiv((long long)N * 64, 256), 256, 0, stream>>>(h2, as2w, ad2w, a_s2, a_d2, N);
  k_score2<<<cdiv(ET, 256), 256, 0, stream>>>(ei, E, ET, a_s2, a_d2, e2, m2);
  k_soft2<<<cdiv(ET, 256), 256, 0, stream>>>(ei, E, ET, e2, m2, dn2);
  k_agg2<<<cdiv((long long)ET * 64, 256), 256, 0, stream>>>(ei, E, ET, e2, dn2, h2, agg2);

  k_final<<<cdiv((long long)N * OUT_D, 256), 256, 0, stream>>>(agg2, b2, out, (long long)N * OUT_D);
}

// Round 3
// 983.573 us; speedup vs baseline: 1.7869x; 1.7869x over previous
//
#include <hip/hip_runtime.h>
#include <hip/hip_bf16.h>
#include <cstdint>
#include <cstddef>

#define IN_D 256
#define HID 128
#define OUT_D 64
#define NSLOPE 0.2f
#define NEG_BIG -3.0e38f

static inline int cdiv(long long a, long long b) { return (int)((a + b - 1) / b); }

// Edge i -> (src, dst); harness delivers edge_index as int32, layout [2, E].
// Self-loops appended logically for i >= E.
__device__ __forceinline__ void edge_sd(const int* __restrict__ ei, int E, int i,
                                        int& s, int& d) {
  if (i < E) { s = ei[i]; d = ei[E + i]; }
  else       { s = i - E; d = s; }
}

__device__ __forceinline__ float lrelu(float v) { return v >= 0.f ? v : NSLOPE * v; }

// ---------------- CSR build ----------------
__global__ void k_initdeg(int* deg, int N) {
  int i = blockIdx.x * blockDim.x + threadIdx.x;
  if (i < N) deg[i] = 1;  // self-loop
}

__global__ void k_hist(const int* __restrict__ ei, int E, int* __restrict__ deg) {
  int i = blockIdx.x * blockDim.x + threadIdx.x;
  if (i < E) atomicAdd(&deg[ei[E + i]], 1);
}

#define SBS 256
__global__ void k_bsum(const int* __restrict__ deg, int* __restrict__ bsum, int N) {
  int i = blockIdx.x * SBS + threadIdx.x;
  int v = (i < N) ? deg[i] : 0;
  #pragma unroll
  for (int o = 32; o; o >>= 1) v += __shfl_xor(v, o);
  __shared__ int sh[4];
  if ((threadIdx.x & 63) == 0) sh[threadIdx.x >> 6] = v;
  __syncthreads();
  if (threadIdx.x == 0) bsum[blockIdx.x] = sh[0] + sh[1] + sh[2] + sh[3];
}

// single block, 512 threads: exclusive scan of bsum[0..NB), write total to roN
__global__ void k_bscan(int* __restrict__ bsum, int NB, int* __restrict__ roN) {
  __shared__ int sh[512];
  int t = threadIdx.x;
  int v = (t < NB) ? bsum[t] : 0;
  sh[t] = v; __syncthreads();
  for (int o = 1; o < 512; o <<= 1) {
    int add = (t >= o) ? sh[t - o] : 0;
    __syncthreads();
    sh[t] += add;
    __syncthreads();
  }
  if (t < NB) bsum[t] = sh[t] - v;   // exclusive
  if (t == 511) *roN = sh[511];      // total = ET
}

__global__ void k_bscan3(const int* __restrict__ deg, const int* __restrict__ bsum,
                         int* __restrict__ ro, int* __restrict__ cur, int N) {
  int i = blockIdx.x * SBS + threadIdx.x;
  int v = (i < N) ? deg[i] : 0;
  __shared__ int sh[SBS];
  sh[threadIdx.x] = v; __syncthreads();
  for (int o = 1; o < SBS; o <<= 1) {
    int add = (threadIdx.x >= o) ? sh[threadIdx.x - o] : 0;
    __syncthreads();
    sh[threadIdx.x] += add;
    __syncthreads();
  }
  if (i < N) {
    int r = sh[threadIdx.x] - v + bsum[blockIdx.x];
    ro[i] = r; cur[i] = r;
  }
}

__global__ void k_scatter(const int* __restrict__ ei, int E, int ET,
                          int* __restrict__ cur, int* __restrict__ col) {
  int i = blockIdx.x * blockDim.x + threadIdx.x;
  if (i >= ET) return;
  int s, d; edge_sd(ei, E, i, s, d);
  int pos = atomicAdd(&cur[d], 1);
  col[pos] = s;
}

// ---------------- Layer 1: GEMM + fused logits ----------------
// h1 = x @ W1 ; epilogue computes a_s1/a_d1 = h1 . att vectors
__launch_bounds__(256)
__global__ void k_gemm1(const float* __restrict__ x, const float* __restrict__ W,
                        const float* __restrict__ as1, const float* __restrict__ ad1,
                        float* __restrict__ h, float* __restrict__ a_s,
                        float* __restrict__ a_d, int N) {
  __shared__ float xs[8][IN_D];
  int tid = threadIdx.x;
  int row0 = blockIdx.x * 8;
  #pragma unroll
  for (int r = 0; r < 8; ++r) {
    int n = row0 + r;
    xs[r][tid] = (n < N) ? x[(size_t)n * IN_D + tid] : 0.f;
  }
  __syncthreads();
  float acc[8] = {};
  for (int k = 0; k < IN_D; ++k) {
    float w = W[(size_t)k * IN_D + tid];
    #pragma unroll
    for (int r = 0; r < 8; ++r) acc[r] += xs[r][k] * w;
  }
  #pragma unroll
  for (int r = 0; r < 8; ++r) {
    int n = row0 + r;
    if (n < N) h[(size_t)n * IN_D + tid] = acc[r];
  }
  // fused logits: per row r, dot(acc_over_c, att[c]); waves 0-1 = head0, 2-3 = head1
  float asv = as1[tid], adv = ad1[tid];
  __shared__ float red[2][8][4];
  int wv = tid >> 6, lane = tid & 63;
  #pragma unroll
  for (int r = 0; r < 8; ++r) {
    float ps = acc[r] * asv, pd = acc[r] * adv;
    #pragma unroll
    for (int o = 32; o; o >>= 1) { ps += __shfl_xor(ps, o); pd += __shfl_xor(pd, o); }
    if (lane == 0) { red[0][r][wv] = ps; red[1][r][wv] = pd; }
  }
  __syncthreads();
  if (tid < 16) {
    int r = tid >> 1, hd = tid & 1;
    int n = row0 + r;
    if (n < N) {
      a_s[n * 2 + hd] = red[0][r][hd * 2] + red[0][r][hd * 2 + 1];
      a_d[n * 2 + hd] = red[1][r][hd * 2] + red[1][r][hd * 2 + 1];
    }
  }
}

// ---------------- Layer 1: fused edge pipeline (one wave per dst node) ------
// softmax over in-edges + weighted gather of h[src] + head-mean, no atomics
__launch_bounds__(256)
__global__ void k_fagg1(const int* __restrict__ ro, const int* __restrict__ col,
                        const float* __restrict__ a_s, const float* __restrict__ a_d,
                        const float* __restrict__ h, float* __restrict__ aggm, int N) {
  int gid = blockIdx.x * blockDim.x + threadIdx.x;
  int n = gid >> 6, lane = gid & 63;
  if (n >= N) return;
  int beg = ro[n], end = ro[n + 1];
  float ad0 = a_d[2 * n], ad1 = a_d[2 * n + 1];

  // pass 1: online softmax (per-lane, then wave merge)
  float m0 = NEG_BIG, s0 = 0.f, m1 = NEG_BIG, s1 = 0.f;
  for (int j = beg + lane; j < end; j += 64) {
    int sidx = col[j];
    float2 asv = *(const float2*)&a_s[2 * sidx];
    float v0 = lrelu(asv.x + ad0);
    float v1 = lrelu(asv.y + ad1);
    float nm0 = fmaxf(m0, v0); s0 = s0 * __expf(m0 - nm0) + __expf(v0 - nm0); m0 = nm0;
    float nm1 = fmaxf(m1, v1); s1 = s1 * __expf(m1 - nm1) + __expf(v1 - nm1); m1 = nm1;
  }
  #pragma unroll
  for (int o = 32; o; o >>= 1) {
    float om0 = __shfl_xor(m0, o), os0 = __shfl_xor(s0, o);
    float nm0 = fmaxf(m0, om0);
    s0 = s0 * __expf(m0 - nm0) + os0 * __expf(om0 - nm0); m0 = nm0;
    float om1 = __shfl_xor(m1, o), os1 = __shfl_xor(s1, o);
    float nm1 = fmaxf(m1, om1);
    s1 = s1 * __expf(m1 - nm1) + os1 * __expf(om1 - nm1); m1 = nm1;
  }

  // pass 2: weighted gather. Lanes 0-31: head0 channels, 32-63: head1 channels.
  bool hi = lane >= 32;
  float myM = hi ? m1 : m0;
  float rcp = 1.f / (hi ? s1 : s0);
  float myAd = hi ? ad1 : ad0;
  int sub = hi ? 1 : 0;
  float4 acc = {0.f, 0.f, 0.f, 0.f};
  for (int j = beg; j < end; ++j) {
    int sidx = col[j];  // broadcast across wave
    float v = lrelu(a_s[2 * sidx + sub] + myAd);
    float al = __expf(v - myM) * rcp;
    const float4 hv = *(const float4*)&h[(size_t)sidx * IN_D + lane * 4];
    acc.x += al * hv.x; acc.y += al * hv.y; acc.z += al * hv.z; acc.w += al * hv.w;
  }
  // head-mean: lane l (<32) channels 4l..4l+3 head0; lane l+32 same channels head1
  acc.x += __shfl_xor(acc.x, 32);
  acc.y += __shfl_xor(acc.y, 32);
  acc.z += __shfl_xor(acc.z, 32);
  acc.w += __shfl_xor(acc.w, 32);
  if (lane < 32) {
    float4 o = {0.5f * acc.x, 0.5f * acc.y, 0.5f * acc.z, 0.5f * acc.w};
    *(float4*)&aggm[(size_t)n * HID + lane * 4] = o;
  }
}

// ---------------- Layer 2: GEMM + fused logits ----------------
// h2 = relu(aggm + b1) @ W2 ; epilogue computes a_s2/a_d2
__launch_bounds__(256)
__global__ void k_gemm2(const float* __restrict__ aggm, const float* __restrict__ b1,
                        const float* __restrict__ W2, const float* __restrict__ as2,
                        const float* __restrict__ ad2, float* __restrict__ h2,
                        float* __restrict__ a_s, float* __restrict__ a_d, int N) {
  __shared__ float xs[16][HID];
  int tid = threadIdx.x;
  int row0 = blockIdx.x * 16;
  for (int t = tid; t < 16 * HID; t += 256) {
    int r = t >> 7, k = t & 127;
    int n = row0 + r;
    float v = 0.f;
    if (n < N) {
      v = aggm[(size_t)n * HID + k] + b1[k];
      v = (v > 0.f) ? v : 0.f;
    }
    xs[r][k] = v;
  }
  __syncthreads();
  int c = tid & 63, rs = tid >> 6;  // wave rs handles rows rs + 4q
  float acc[4] = {};
  for (int k = 0; k < HID; ++k) {
    float w = W2[(size_t)k * OUT_D + c];
    #pragma unroll
    for (int q = 0; q < 4; ++q) acc[q] += xs[rs + q * 4][k] * w;
  }
  float asv = as2[c], adv = ad2[c];
  #pragma unroll
  for (int q = 0; q < 4; ++q) {
    int n = row0 + rs + q * 4;
    if (n < N) h2[(size_t)n * OUT_D + c] = acc[q];
    float ps = acc[q] * asv, pd = acc[q] * adv;
    #pragma unroll
    for (int o = 32; o; o >>= 1) { ps += __shfl_xor(ps, o); pd += __shfl_xor(pd, o); }
    if (c == 0 && n < N) { a_s[n] = ps; a_d[n] = pd; }
  }
}

// ---------------- Layer 2: fused edge pipeline + bias -> out ----------------
__launch_bounds__(256)
__global__ void k_fagg2(const int* __restrict__ ro, const int* __restrict__ col,
                        const float* __restrict__ a_s, const float* __restrict__ a_d,
                        const float* __restrict__ h2, const float* __restrict__ b2,
                        float* __restrict__ out, int N) {
  int gid = blockIdx.x * blockDim.x + threadIdx.x;
  int n = gid >> 6, lane = gid & 63;
  if (n >= N) return;
  int beg = ro[n], end = ro[n + 1];
  float ad = a_d[n];

  float m = NEG_BIG, s = 0.f;
  for (int j = beg + lane; j < end; j += 64) {
    float v = lrelu(a_s[col[j]] + ad);
    float nm = fmaxf(m, v); s = s * __expf(m - nm) + __expf(v - nm); m = nm;
  }
  #pragma unroll
  for (int o = 32; o; o >>= 1) {
    float om = __shfl_xor(m, o), os = __shfl_xor(s, o);
    float nm = fmaxf(m, om);
    s = s * __expf(m - nm) + os * __expf(om - nm); m = nm;
  }
  float rcp = 1.f / s;
  float acc = 0.f;
  for (int j = beg; j < end; ++j) {
    int sidx = col[j];
    float v = lrelu(a_s[sidx] + ad);
    float al = __expf(v - m) * rcp;
    acc += al * h2[(size_t)sidx * OUT_D + lane];
  }
  out[(size_t)n * OUT_D + lane] = acc + b2[lane];
}

extern "C" void kernel_launch(void* const* d_in, const int* in_sizes, int n_in,
                              void* d_out, int out_size, void* d_ws, size_t ws_size,
                              hipStream_t stream) {
  const float* x    = (const float*)d_in[0];
  const int*   ei   = (const int*)d_in[1];    // harness converts int64 -> int32
  const float* W1   = (const float*)d_in[2];
  const float* as1w = (const float*)d_in[3];
  const float* ad1w = (const float*)d_in[4];
  const float* b1   = (const float*)d_in[5];
  const float* W2   = (const float*)d_in[6];
  const float* as2w = (const float*)d_in[7];
  const float* ad2w = (const float*)d_in[8];
  const float* b2   = (const float*)d_in[9];
  float* out = (float*)d_out;

  const int N  = in_sizes[0] / IN_D;
  const int E  = in_sizes[1] / 2;
  const int ET = E + N;
  const int NB = cdiv(N, SBS);  // 391 <= 512

  // Workspace layout (element offsets; all 4-byte types). ~164 MB.
  float* ws = (float*)d_ws;
  size_t off = 0;
  float* h1   = ws + off; off += (size_t)N * IN_D;   // h2 aliases h1 (dead after fagg1)
  float* aggm = ws + off; off += (size_t)N * HID;
  float* a_s1 = ws + off; off += (size_t)N * 2;
  float* a_d1 = ws + off; off += (size_t)N * 2;
  float* a_s2 = ws + off; off += N;
  float* a_d2 = ws + off; off += N;
  int*   deg  = (int*)(ws + off); off += N;
  int*   ro   = (int*)(ws + off); off += (size_t)N + 1;
  int*   cur  = (int*)(ws + off); off += N;
  int*   col  = (int*)(ws + off); off += ET;
  int*   bsum = (int*)(ws + off); off += 512;

  float* h2 = h1;

  // CSR build (group edges by dst; self-loops included via deg init = 1)
  k_initdeg<<<cdiv(N, 256), 256, 0, stream>>>(deg, N);
  k_hist<<<cdiv(E, 256), 256, 0, stream>>>(ei, E, deg);
  k_bsum<<<NB, SBS, 0, stream>>>(deg, bsum, N);
  k_bscan<<<1, 512, 0, stream>>>(bsum, NB, ro + N);
  k_bscan3<<<NB, SBS, 0, stream>>>(deg, bsum, ro, cur, N);
  k_scatter<<<cdiv(ET, 256), 256, 0, stream>>>(ei, E, ET, cur, col);

  // Layer 1
  k_gemm1<<<cdiv(N, 8), 256, 0, stream>>>(x, W1, as1w, ad1w, h1, a_s1, a_d1, N);
  k_fagg1<<<cdiv((long long)N * 64, 256), 256, 0, stream>>>(ro, col, a_s1, a_d1, h1, aggm, N);

  // Layer 2
  k_gemm2<<<cdiv(N, 16), 256, 0, stream>>>(aggm, b1, W2, as2w, ad2w, h2, a_s2, a_d2, N);
  k_fagg2<<<cdiv((long long)N * 64, 256), 256, 0, stream>>>(ro, col, a_s2, a_d2, h2, b2, out, N);
}

// Round 4
// 969.470 us; speedup vs baseline: 1.8129x; 1.0145x over previous
//
#include <hip/hip_runtime.h>
#include <hip/hip_bf16.h>
#include <cstdint>
#include <cstddef>

#define IN_D 256
#define HID 128
#define OUT_D 64
#define NSLOPE 0.2f
#define NEG_BIG -3.0e38f

typedef __attribute__((ext_vector_type(8))) short bf16x8;
typedef __attribute__((ext_vector_type(4))) float f32x4;

static inline int cdiv(long long a, long long b) { return (int)((a + b - 1) / b); }

__device__ __forceinline__ void edge_sd(const int* __restrict__ ei, int E, int i,
                                        int& s, int& d) {
  if (i < E) { s = ei[i]; d = ei[E + i]; }
  else       { s = i - E; d = s; }
}

__device__ __forceinline__ float lrelu(float v) { return v >= 0.f ? v : NSLOPE * v; }

// f32 -> bf16 (RNE) via bit ops (avoids hip_bf16 API variance)
__device__ __forceinline__ unsigned short f2bf(float f) {
  unsigned u = __float_as_uint(f);
  return (unsigned short)((u + 0x7FFFu + ((u >> 16) & 1u)) >> 16);
}
__device__ __forceinline__ float bf2f(unsigned short h) {
  return __uint_as_float((unsigned)h << 16);
}

// ---------------- CSR build ----------------
__global__ void k_initdeg(int* deg, int N) {
  int i = blockIdx.x * blockDim.x + threadIdx.x;
  if (i < N) deg[i] = 1;  // self-loop
}

__global__ void k_hist(const int* __restrict__ ei, int E, int* __restrict__ deg) {
  int i = blockIdx.x * blockDim.x + threadIdx.x;
  if (i < E) atomicAdd(&deg[ei[E + i]], 1);
}

#define SBS 256
__global__ void k_bsum(const int* __restrict__ deg, int* __restrict__ bsum, int N) {
  int i = blockIdx.x * SBS + threadIdx.x;
  int v = (i < N) ? deg[i] : 0;
  #pragma unroll
  for (int o = 32; o; o >>= 1) v += __shfl_xor(v, o);
  __shared__ int sh[4];
  if ((threadIdx.x & 63) == 0) sh[threadIdx.x >> 6] = v;
  __syncthreads();
  if (threadIdx.x == 0) bsum[blockIdx.x] = sh[0] + sh[1] + sh[2] + sh[3];
}

__global__ void k_bscan(int* __restrict__ bsum, int NB, int* __restrict__ roN) {
  __shared__ int sh[512];
  int t = threadIdx.x;
  int v = (t < NB) ? bsum[t] : 0;
  sh[t] = v; __syncthreads();
  for (int o = 1; o < 512; o <<= 1) {
    int add = (t >= o) ? sh[t - o] : 0;
    __syncthreads();
    sh[t] += add;
    __syncthreads();
  }
  if (t < NB) bsum[t] = sh[t] - v;   // exclusive
  if (t == 511) *roN = sh[511];      // total = ET
}

__global__ void k_bscan3(const int* __restrict__ deg, const int* __restrict__ bsum,
                         int* __restrict__ ro, int* __restrict__ cur, int N) {
  int i = blockIdx.x * SBS + threadIdx.x;
  int v = (i < N) ? deg[i] : 0;
  __shared__ int sh[SBS];
  sh[threadIdx.x] = v; __syncthreads();
  for (int o = 1; o < SBS; o <<= 1) {
    int add = (threadIdx.x >= o) ? sh[threadIdx.x - o] : 0;
    __syncthreads();
    sh[threadIdx.x] += add;
    __syncthreads();
  }
  if (i < N) {
    int r = sh[threadIdx.x] - v + bsum[blockIdx.x];
    ro[i] = r; cur[i] = r;
  }
}

__global__ void k_scatter(const int* __restrict__ ei, int E, int ET,
                          int* __restrict__ cur, int* __restrict__ col) {
  int i = blockIdx.x * blockDim.x + threadIdx.x;
  if (i >= ET) return;
  int s, d; edge_sd(ei, E, i, s, d);
  int pos = atomicAdd(&cur[d], 1);
  col[pos] = s;
}

// ---------------- W1 prep: transpose + split to bf16 hi/lo -----------------
// W [K=256][N=256] row-major  ->  WT_hi/WT_lo [N][K] bf16
__global__ void k_prepW(const float* __restrict__ W, unsigned short* __restrict__ WThi,
                        unsigned short* __restrict__ WTlo) {
  int idx = blockIdx.x * 256 + threadIdx.x;
  if (idx >= IN_D * IN_D) return;
  int k = idx >> 8, n = idx & 255;
  float f = W[idx];
  unsigned short h = f2bf(f);
  unsigned short lo = f2bf(f - bf2f(h));
  WThi[n * IN_D + k] = h;
  WTlo[n * IN_D + k] = lo;
}

// ---------------- Layer 1: MFMA GEMM (split-bf16) + fused logits ------------
// h1 = x @ W1 via xh@Wh + xl@Wh + xh@Wl. Block = 4 waves x 16 rows = 64 rows.
__launch_bounds__(256)
__global__ void k_gemm1(const float* __restrict__ x, const unsigned short* __restrict__ WThi,
                        const unsigned short* __restrict__ WTlo,
                        const float* __restrict__ as1, const float* __restrict__ ad1,
                        float* __restrict__ h, float* __restrict__ a_s,
                        float* __restrict__ a_d, int N) {
  int tid = threadIdx.x;
  int w = tid >> 6, l = tid & 63;
  int l15 = l & 15, l4 = l >> 4;
  int rowbase = blockIdx.x * 64 + w * 16;
  int row = rowbase + l15;            // A-fragment row this lane feeds
  int rowc = (row < N) ? row : (N - 1);
  const float* xp = x + (size_t)rowc * IN_D + l4 * 8;

  f32x4 acc[16];
  #pragma unroll
  for (int t = 0; t < 16; ++t) acc[t] = (f32x4){0.f, 0.f, 0.f, 0.f};

  // att vectors: flat idx = t*16 + l15 (head = t>>3 folded into flat layout)
  float asv[16], adv[16];
  #pragma unroll
  for (int t = 0; t < 16; ++t) { asv[t] = as1[t * 16 + l15]; adv[t] = ad1[t * 16 + l15]; }

  for (int kk = 0; kk < 8; ++kk) {
    f32x4 v0 = *(const f32x4*)(xp + kk * 32);
    f32x4 v1 = *(const f32x4*)(xp + kk * 32 + 4);
    bf16x8 ah, al;
    #pragma unroll
    for (int j = 0; j < 4; ++j) {
      unsigned short h0 = f2bf(v0[j]);
      ah[j] = (short)h0; al[j] = (short)f2bf(v0[j] - bf2f(h0));
      unsigned short h1 = f2bf(v1[j]);
      ah[j + 4] = (short)h1; al[j + 4] = (short)f2bf(v1[j] - bf2f(h1));
    }
    size_t boff = (size_t)l15 * IN_D + kk * 32 + l4 * 8;
    #pragma unroll
    for (int t = 0; t < 16; ++t) {
      bf16x8 bh = *(const bf16x8*)(WThi + boff + (size_t)t * 16 * IN_D);
      bf16x8 bl = *(const bf16x8*)(WTlo + boff + (size_t)t * 16 * IN_D);
      acc[t] = __builtin_amdgcn_mfma_f32_16x16x32_bf16(ah, bh, acc[t], 0, 0, 0);
      acc[t] = __builtin_amdgcn_mfma_f32_16x16x32_bf16(al, bh, acc[t], 0, 0, 0);
      acc[t] = __builtin_amdgcn_mfma_f32_16x16x32_bf16(ah, bl, acc[t], 0, 0, 0);
    }
  }

  // ---- epilogue: store h (D layout: row=(l>>4)*4+r, col=t*16+l15) ----
  #pragma unroll
  for (int r = 0; r < 4; ++r) {
    int rr = rowbase + l4 * 4 + r;
    if (rr < N) {
      float* hp = h + (size_t)rr * IN_D + l15;
      #pragma unroll
      for (int t = 0; t < 16; ++t) hp[t * 16] = acc[t][r];
    }
  }
  // ---- fused logits: per-head dots, reduce across the 16 col-lanes ----
  float ps0[4] = {}, ps1[4] = {}, pd0[4] = {}, pd1[4] = {};
  #pragma unroll
  for (int t = 0; t < 16; ++t) {
    #pragma unroll
    for (int r = 0; r < 4; ++r) {
      float v = acc[t][r];
      if (t < 8) { ps0[r] += v * asv[t]; pd0[r] += v * adv[t]; }
      else       { ps1[r] += v * asv[t]; pd1[r] += v * adv[t]; }
    }
  }
  #pragma unroll
  for (int r = 0; r < 4; ++r) {
    #pragma unroll
    for (int o = 1; o < 16; o <<= 1) {
      ps0[r] += __shfl_xor(ps0[r], o); ps1[r] += __shfl_xor(ps1[r], o);
      pd0[r] += __shfl_xor(pd0[r], o); pd1[r] += __shfl_xor(pd1[r], o);
    }
    int rr = rowbase + l4 * 4 + r;
    if (l15 == 0 && rr < N) {
      a_s[rr * 2] = ps0[r]; a_s[rr * 2 + 1] = ps1[r];
      a_d[rr * 2] = pd0[r]; a_d[rr * 2 + 1] = pd1[r];
    }
  }
}

// ---------------- Layer 1: fused edge pipeline (one wave per dst node) ------
__launch_bounds__(256)
__global__ void k_fagg1(const int* __restrict__ ro, const int* __restrict__ col,
                        const float* __restrict__ a_s, const float* __restrict__ a_d,
                        const float* __restrict__ h, float* __restrict__ aggm, int N) {
  int gid = blockIdx.x * blockDim.x + threadIdx.x;
  int n = gid >> 6, lane = gid & 63;
  if (n >= N) return;
  int beg = ro[n], end = ro[n + 1];
  float ad0 = a_d[2 * n], ad1 = a_d[2 * n + 1];

  float m0 = NEG_BIG, s0 = 0.f, m1 = NEG_BIG, s1 = 0.f;
  for (int j = beg + lane; j < end; j += 64) {
    int sidx = col[j];
    float2 asv = *(const float2*)&a_s[2 * sidx];
    float v0 = lrelu(asv.x + ad0);
    float v1 = lrelu(asv.y + ad1);
    float nm0 = fmaxf(m0, v0); s0 = s0 * __expf(m0 - nm0) + __expf(v0 - nm0); m0 = nm0;
    float nm1 = fmaxf(m1, v1); s1 = s1 * __expf(m1 - nm1) + __expf(v1 - nm1); m1 = nm1;
  }
  #pragma unroll
  for (int o = 32; o; o >>= 1) {
    float om0 = __shfl_xor(m0, o), os0 = __shfl_xor(s0, o);
    float nm0 = fmaxf(m0, om0);
    s0 = s0 * __expf(m0 - nm0) + os0 * __expf(om0 - nm0); m0 = nm0;
    float om1 = __shfl_xor(m1, o), os1 = __shfl_xor(s1, o);
    float nm1 = fmaxf(m1, om1);
    s1 = s1 * __expf(m1 - nm1) + os1 * __expf(om1 - nm1); m1 = nm1;
  }

  bool hi = lane >= 32;
  float myM = hi ? m1 : m0;
  float rcp = 1.f / (hi ? s1 : s0);
  float myAd = hi ? ad1 : ad0;
  int sub = hi ? 1 : 0;
  float4 acc = {0.f, 0.f, 0.f, 0.f};
  for (int j = beg; j < end; ++j) {
    int sidx = col[j];  // broadcast across wave
    float v = lrelu(a_s[2 * sidx + sub] + myAd);
    float al = __expf(v - myM) * rcp;
    const float4 hv = *(const float4*)&h[(size_t)sidx * IN_D + lane * 4];
    acc.x += al * hv.x; acc.y += al * hv.y; acc.z += al * hv.z; acc.w += al * hv.w;
  }
  acc.x += __shfl_xor(acc.x, 32);
  acc.y += __shfl_xor(acc.y, 32);
  acc.z += __shfl_xor(acc.z, 32);
  acc.w += __shfl_xor(acc.w, 32);
  if (lane < 32) {
    float4 o = {0.5f * acc.x, 0.5f * acc.y, 0.5f * acc.z, 0.5f * acc.w};
    *(float4*)&aggm[(size_t)n * HID + lane * 4] = o;
  }
}

// ---------------- Layer 2: GEMM + fused logits ----------------
__launch_bounds__(256)
__global__ void k_gemm2(const float* __restrict__ aggm, const float* __restrict__ b1,
                        const float* __restrict__ W2, const float* __restrict__ as2,
                        const float* __restrict__ ad2, float* __restrict__ h2,
                        float* __restrict__ a_s, float* __restrict__ a_d, int N) {
  __shared__ float xs[16][HID];
  int tid = threadIdx.x;
  int row0 = blockIdx.x * 16;
  for (int t = tid; t < 16 * HID; t += 256) {
    int r = t >> 7, k = t & 127;
    int n = row0 + r;
    float v = 0.f;
    if (n < N) {
      v = aggm[(size_t)n * HID + k] + b1[k];
      v = (v > 0.f) ? v : 0.f;
    }
    xs[r][k] = v;
  }
  __syncthreads();
  int c = tid & 63, rs = tid >> 6;
  float acc[4] = {};
  for (int k = 0; k < HID; ++k) {
    float w = W2[(size_t)k * OUT_D + c];
    #pragma unroll
    for (int q = 0; q < 4; ++q) acc[q] += xs[rs + q * 4][k] * w;
  }
  float asv = as2[c], adv = ad2[c];
  #pragma unroll
  for (int q = 0; q < 4; ++q) {
    int n = row0 + rs + q * 4;
    if (n < N) h2[(size_t)n * OUT_D + c] = acc[q];
    float ps = acc[q] * asv, pd = acc[q] * adv;
    #pragma unroll
    for (int o = 32; o; o >>= 1) { ps += __shfl_xor(ps, o); pd += __shfl_xor(pd, o); }
    if (c == 0 && n < N) { a_s[n] = ps; a_d[n] = pd; }
  }
}

// ---------------- Layer 2: fused edge pipeline + bias -> out ----------------
__launch_bounds__(256)
__global__ void k_fagg2(const int* __restrict__ ro, const int* __restrict__ col,
                        const float* __restrict__ a_s, const float* __restrict__ a_d,
                        const float* __restrict__ h2, const float* __restrict__ b2,
                        float* __restrict__ out, int N) {
  int gid = blockIdx.x * blockDim.x + threadIdx.x;
  int n = gid >> 6, lane = gid & 63;
  if (n >= N) return;
  int beg = ro[n], end = ro[n + 1];
  float ad = a_d[n];

  float m = NEG_BIG, s = 0.f;
  for (int j = beg + lane; j < end; j += 64) {
    float v = lrelu(a_s[col[j]] + ad);
    float nm = fmaxf(m, v); s = s * __expf(m - nm) + __expf(v - nm); m = nm;
  }
  #pragma unroll
  for (int o = 32; o; o >>= 1) {
    float om = __shfl_xor(m, o), os = __shfl_xor(s, o);
    float nm = fmaxf(m, om);
    s = s * __expf(m - nm) + os * __expf(om - nm); m = nm;
  }
  float rcp = 1.f / s;
  float acc = 0.f;
  for (int j = beg; j < end; ++j) {
    int sidx = col[j];
    float v = lrelu(a_s[sidx] + ad);
    float al = __expf(v - m) * rcp;
    acc += al * h2[(size_t)sidx * OUT_D + lane];
  }
  out[(size_t)n * OUT_D + lane] = acc + b2[lane];
}

extern "C" void kernel_launch(void* const* d_in, const int* in_sizes, int n_in,
                              void* d_out, int out_size, void* d_ws, size_t ws_size,
                              hipStream_t stream) {
  const float* x    = (const float*)d_in[0];
  const int*   ei   = (const int*)d_in[1];    // harness converts int64 -> int32
  const float* W1   = (const float*)d_in[2];
  const float* as1w = (const float*)d_in[3];
  const float* ad1w = (const float*)d_in[4];
  const float* b1   = (const float*)d_in[5];
  const float* W2   = (const float*)d_in[6];
  const float* as2w = (const float*)d_in[7];
  const float* ad2w = (const float*)d_in[8];
  const float* b2   = (const float*)d_in[9];
  float* out = (float*)d_out;

  const int N  = in_sizes[0] / IN_D;
  const int E  = in_sizes[1] / 2;
  const int ET = E + N;
  const int NB = cdiv(N, SBS);

  // Workspace layout (element offsets; all 4-byte types). ~164 MB.
  float* ws = (float*)d_ws;
  size_t off = 0;
  float* h1   = ws + off; off += (size_t)N * IN_D;   // h2 aliases h1 (dead after fagg1)
  float* aggm = ws + off; off += (size_t)N * HID;
  float* a_s1 = ws + off; off += (size_t)N * 2;
  float* a_d1 = ws + off; off += (size_t)N * 2;
  float* a_s2 = ws + off; off += N;
  float* a_d2 = ws + off; off += N;
  int*   deg  = (int*)(ws + off); off += N;
  int*   ro   = (int*)(ws + off); off += (size_t)N + 1;
  int*   cur  = (int*)(ws + off); off += N;
  int*   col  = (int*)(ws + off); off += ET;
  int*   bsum = (int*)(ws + off); off += 512;
  unsigned short* WThi = (unsigned short*)(ws + off); off += (IN_D * IN_D) / 2;
  unsigned short* WTlo = (unsigned short*)(ws + off); off += (IN_D * IN_D) / 2;

  float* h2 = h1;

  // CSR build (group edges by dst; self-loops included via deg init = 1)
  k_initdeg<<<cdiv(N, 256), 256, 0, stream>>>(deg, N);
  k_hist<<<cdiv(E, 256), 256, 0, stream>>>(ei, E, deg);
  k_bsum<<<NB, SBS, 0, stream>>>(deg, bsum, N);
  k_bscan<<<1, 512, 0, stream>>>(bsum, NB, ro + N);
  k_bscan3<<<NB, SBS, 0, stream>>>(deg, bsum, ro, cur, N);
  k_scatter<<<cdiv(ET, 256), 256, 0, stream>>>(ei, E, ET, cur, col);

  // Layer 1
  k_prepW<<<cdiv(IN_D * IN_D, 256), 256, 0, stream>>>(W1, WThi, WTlo);
  k_gemm1<<<cdiv(N, 64), 256, 0, stream>>>(x, WThi, WTlo, as1w, ad1w, h1, a_s1, a_d1, N);
  k_fagg1<<<cdiv((long long)N * 64, 256), 256, 0, stream>>>(ro, col, a_s1, a_d1, h1, aggm, N);

  // Layer 2
  k_gemm2<<<cdiv(N, 16), 256, 0, stream>>>(aggm, b1, W2, as2w, ad2w, h2, a_s2, a_d2, N);
  k_fagg2<<<cdiv((long long)N * 64, 256), 256, 0, stream>>>(ro, col, a_s2, a_d2, h2, b2, out, N);
}

// Round 5
// 717.825 us; speedup vs baseline: 2.4485x; 1.3506x over previous
//
#include <hip/hip_runtime.h>
#include <hip/hip_bf16.h>
#include <cstdint>
#include <cstddef>

#define IN_D 256
#define HID 128
#define OUT_D 64
#define NSLOPE 0.2f
#define NEG_BIG -3.0e38f

typedef __attribute__((ext_vector_type(8))) short bf16x8;
typedef __attribute__((ext_vector_type(4))) float f32x4;
typedef unsigned short u16;

static inline int cdiv(long long a, long long b) { return (int)((a + b - 1) / b); }

__device__ __forceinline__ void edge_sd(const int* __restrict__ ei, int E, int i,
                                        int& s, int& d) {
  if (i < E) { s = ei[i]; d = ei[E + i]; }
  else       { s = i - E; d = s; }
}

__device__ __forceinline__ float lrelu(float v) { return v >= 0.f ? v : NSLOPE * v; }

// f32 -> bf16 (RNE) via bit ops
__device__ __forceinline__ u16 f2bf(float f) {
  unsigned u = __float_as_uint(f);
  return (u16)((u + 0x7FFFu + ((u >> 16) & 1u)) >> 16);
}
__device__ __forceinline__ float bf2f(u16 h) {
  return __uint_as_float((unsigned)h << 16);
}

// ---------------- CSR build ----------------
__global__ void k_initdeg(int* deg, int N) {
  int i = blockIdx.x * blockDim.x + threadIdx.x;
  if (i < N) deg[i] = 1;  // self-loop
}

__global__ void k_hist(const int* __restrict__ ei, int E, int* __restrict__ deg) {
  int i = blockIdx.x * blockDim.x + threadIdx.x;
  if (i < E) atomicAdd(&deg[ei[E + i]], 1);
}

#define SBS 256
__global__ void k_bsum(const int* __restrict__ deg, int* __restrict__ bsum, int N) {
  int i = blockIdx.x * SBS + threadIdx.x;
  int v = (i < N) ? deg[i] : 0;
  #pragma unroll
  for (int o = 32; o; o >>= 1) v += __shfl_xor(v, o);
  __shared__ int sh[4];
  if ((threadIdx.x & 63) == 0) sh[threadIdx.x >> 6] = v;
  __syncthreads();
  if (threadIdx.x == 0) bsum[blockIdx.x] = sh[0] + sh[1] + sh[2] + sh[3];
}

__global__ void k_bscan(int* __restrict__ bsum, int NB, int* __restrict__ roN) {
  __shared__ int sh[512];
  int t = threadIdx.x;
  int v = (t < NB) ? bsum[t] : 0;
  sh[t] = v; __syncthreads();
  for (int o = 1; o < 512; o <<= 1) {
    int add = (t >= o) ? sh[t - o] : 0;
    __syncthreads();
    sh[t] += add;
    __syncthreads();
  }
  if (t < NB) bsum[t] = sh[t] - v;   // exclusive
  if (t == 511) *roN = sh[511];      // total = ET
}

__global__ void k_bscan3(const int* __restrict__ deg, const int* __restrict__ bsum,
                         int* __restrict__ ro, int* __restrict__ cur, int N) {
  int i = blockIdx.x * SBS + threadIdx.x;
  int v = (i < N) ? deg[i] : 0;
  __shared__ int sh[SBS];
  sh[threadIdx.x] = v; __syncthreads();
  for (int o = 1; o < SBS; o <<= 1) {
    int add = (threadIdx.x >= o) ? sh[threadIdx.x - o] : 0;
    __syncthreads();
    sh[threadIdx.x] += add;
    __syncthreads();
  }
  if (i < N) {
    int r = sh[threadIdx.x] - v + bsum[blockIdx.x];
    ro[i] = r; cur[i] = r;
  }
}

__global__ void k_scatter(const int* __restrict__ ei, int E, int ET,
                          int* __restrict__ cur, int* __restrict__ col) {
  int i = blockIdx.x * blockDim.x + threadIdx.x;
  if (i >= ET) return;
  int s, d; edge_sd(ei, E, i, s, d);
  int pos = atomicAdd(&cur[d], 1);
  col[pos] = s;
}

// ---------------- W1 prep: transpose + split to bf16 hi/lo -----------------
// W [K=256][N=256] row-major  ->  WT_hi/WT_lo [N][K] bf16
__global__ void k_prepW(const float* __restrict__ W, u16* __restrict__ WThi,
                        u16* __restrict__ WTlo) {
  int idx = blockIdx.x * 256 + threadIdx.x;
  if (idx >= IN_D * IN_D) return;
  int k = idx >> 8, n = idx & 255;
  float f = W[idx];
  u16 h = f2bf(f);
  u16 lo = f2bf(f - bf2f(h));
  WThi[n * IN_D + k] = h;
  WTlo[n * IN_D + k] = lo;
}

// ---------------- Layer 1: MFMA GEMM (split-bf16), LDS-staged B -------------
// h1(bf16) = x @ W1 via xh@Wh + xl@Wh + xh@Wl. Block = 4 waves x 16 rows.
// Per k-step (32 k's), W hi+lo slice (32KB) is staged in LDS with XOR chunk
// swizzle (slot = ch ^ (n&3)) -> conflict-free ds_write/ds_read_b128.
__launch_bounds__(256)
__global__ void k_gemm1(const float* __restrict__ x, const u16* __restrict__ WThi,
                        const u16* __restrict__ WTlo,
                        const float* __restrict__ as1, const float* __restrict__ ad1,
                        u16* __restrict__ hb, float* __restrict__ a_s,
                        float* __restrict__ a_d, int N) {
  __shared__ u16 ldsb[2][8192];  // [hi/lo][256 rows x 4 slots x 8 bf16] = 32KB
  int tid = threadIdx.x;
  int w = tid >> 6, l = tid & 63;
  int l15 = l & 15, l4 = l >> 4;
  int rowbase = blockIdx.x * 64 + w * 16;
  int row = rowbase + l15;            // A-fragment row this lane feeds
  int rowc = (row < N) ? row : (N - 1);
  const float* xp = x + (size_t)rowc * IN_D + l4 * 8;

  f32x4 acc[16];
  #pragma unroll
  for (int t = 0; t < 16; ++t) acc[t] = (f32x4){0.f, 0.f, 0.f, 0.f};

  // reader LDS index (ushort units): row = t*16+l15, slot = l4 ^ (l15&3)
  const int ridx = (l15 * 4 + (l4 ^ (l15 & 3))) * 8;

  for (int kk = 0; kk < 8; ++kk) {
    // ---- stage W slice (hi+lo) into LDS ----
    __syncthreads();  // previous compute done before overwrite
    #pragma unroll
    for (int it = 0; it < 4; ++it) {
      int c = tid + it * 256;          // chunk id: row n = c>>2, chunk ch = c&3
      int n = c >> 2, ch = c & 3;
      size_t soff = (size_t)n * IN_D + kk * 32 + ch * 8;
      uint4 vh = *(const uint4*)(WThi + soff);
      uint4 vl = *(const uint4*)(WTlo + soff);
      int dsl = (n * 4 + (ch ^ (n & 3))) * 8;  // swizzled slot
      *(uint4*)&ldsb[0][dsl] = vh;
      *(uint4*)&ldsb[1][dsl] = vl;
    }
    __syncthreads();

    // ---- A fragment: load f32, split to bf16 hi/lo ----
    f32x4 v0 = *(const f32x4*)(xp + kk * 32);
    f32x4 v1 = *(const f32x4*)(xp + kk * 32 + 4);
    bf16x8 ah, al;
    #pragma unroll
    for (int j = 0; j < 4; ++j) {
      u16 h0 = f2bf(v0[j]);
      ah[j] = (short)h0; al[j] = (short)f2bf(v0[j] - bf2f(h0));
      u16 h1 = f2bf(v1[j]);
      ah[j + 4] = (short)h1; al[j + 4] = (short)f2bf(v1[j] - bf2f(h1));
    }
    // ---- 16 col-tiles x 3 MFMA ----
    #pragma unroll
    for (int t = 0; t < 16; ++t) {
      bf16x8 bh = *(const bf16x8*)&ldsb[0][ridx + t * 512];
      bf16x8 bl = *(const bf16x8*)&ldsb[1][ridx + t * 512];
      acc[t] = __builtin_amdgcn_mfma_f32_16x16x32_bf16(ah, bh, acc[t], 0, 0, 0);
      acc[t] = __builtin_amdgcn_mfma_f32_16x16x32_bf16(al, bh, acc[t], 0, 0, 0);
      acc[t] = __builtin_amdgcn_mfma_f32_16x16x32_bf16(ah, bl, acc[t], 0, 0, 0);
    }
  }

  // ---- epilogue: store h as bf16 (D layout: row=(l>>4)*4+r, col=t*16+l15) ----
  #pragma unroll
  for (int r = 0; r < 4; ++r) {
    int rr = rowbase + l4 * 4 + r;
    if (rr < N) {
      u16* hp = hb + (size_t)rr * IN_D + l15;
      #pragma unroll
      for (int t = 0; t < 16; ++t) hp[t * 16] = f2bf(acc[t][r]);
    }
  }
  // ---- fused logits ----
  float asv[16], adv[16];
  #pragma unroll
  for (int t = 0; t < 16; ++t) { asv[t] = as1[t * 16 + l15]; adv[t] = ad1[t * 16 + l15]; }
  float ps0[4] = {}, ps1[4] = {}, pd0[4] = {}, pd1[4] = {};
  #pragma unroll
  for (int t = 0; t < 16; ++t) {
    #pragma unroll
    for (int r = 0; r < 4; ++r) {
      float v = acc[t][r];
      if (t < 8) { ps0[r] += v * asv[t]; pd0[r] += v * adv[t]; }
      else       { ps1[r] += v * asv[t]; pd1[r] += v * adv[t]; }
    }
  }
  #pragma unroll
  for (int r = 0; r < 4; ++r) {
    #pragma unroll
    for (int o = 1; o < 16; o <<= 1) {
      ps0[r] += __shfl_xor(ps0[r], o); ps1[r] += __shfl_xor(ps1[r], o);
      pd0[r] += __shfl_xor(pd0[r], o); pd1[r] += __shfl_xor(pd1[r], o);
    }
    int rr = rowbase + l4 * 4 + r;
    if (l15 == 0 && rr < N) {
      a_s[rr * 2] = ps0[r]; a_s[rr * 2 + 1] = ps1[r];
      a_d[rr * 2] = pd0[r]; a_d[rr * 2 + 1] = pd1[r];
    }
  }
}

// ---------------- Layer 1: fused edge pipeline (one wave per dst node) ------
__launch_bounds__(256)
__global__ void k_fagg1(const int* __restrict__ ro, const int* __restrict__ col,
                        const float* __restrict__ a_s, const float* __restrict__ a_d,
                        const u16* __restrict__ hb, float* __restrict__ aggm, int N) {
  int gid = blockIdx.x * blockDim.x + threadIdx.x;
  int n = gid >> 6, lane = gid & 63;
  if (n >= N) return;
  int beg = ro[n], end = ro[n + 1];
  float ad0 = a_d[2 * n], ad1 = a_d[2 * n + 1];

  float m0 = NEG_BIG, s0 = 0.f, m1 = NEG_BIG, s1 = 0.f;
  for (int j = beg + lane; j < end; j += 64) {
    int sidx = col[j];
    float2 asv = *(const float2*)&a_s[2 * sidx];
    float v0 = lrelu(asv.x + ad0);
    float v1 = lrelu(asv.y + ad1);
    float nm0 = fmaxf(m0, v0); s0 = s0 * __expf(m0 - nm0) + __expf(v0 - nm0); m0 = nm0;
    float nm1 = fmaxf(m1, v1); s1 = s1 * __expf(m1 - nm1) + __expf(v1 - nm1); m1 = nm1;
  }
  #pragma unroll
  for (int o = 32; o; o >>= 1) {
    float om0 = __shfl_xor(m0, o), os0 = __shfl_xor(s0, o);
    float nm0 = fmaxf(m0, om0);
    s0 = s0 * __expf(m0 - nm0) + os0 * __expf(om0 - nm0); m0 = nm0;
    float om1 = __shfl_xor(m1, o), os1 = __shfl_xor(s1, o);
    float nm1 = fmaxf(m1, om1);
    s1 = s1 * __expf(m1 - nm1) + os1 * __expf(om1 - nm1); m1 = nm1;
  }

  bool hi = lane >= 32;
  float myM = hi ? m1 : m0;
  float rcp = 1.f / (hi ? s1 : s0);
  float myAd = hi ? ad1 : ad0;
  int sub = hi ? 1 : 0;
  float4 acc = {0.f, 0.f, 0.f, 0.f};
  for (int j = beg; j < end; ++j) {
    int sidx = col[j];  // broadcast across wave
    float v = lrelu(a_s[2 * sidx + sub] + myAd);
    float al = __expf(v - myM) * rcp;
    const ushort4 hv = *(const ushort4*)&hb[(size_t)sidx * IN_D + lane * 4];
    acc.x += al * bf2f(hv.x); acc.y += al * bf2f(hv.y);
    acc.z += al * bf2f(hv.z); acc.w += al * bf2f(hv.w);
  }
  acc.x += __shfl_xor(acc.x, 32);
  acc.y += __shfl_xor(acc.y, 32);
  acc.z += __shfl_xor(acc.z, 32);
  acc.w += __shfl_xor(acc.w, 32);
  if (lane < 32) {
    float4 o = {0.5f * acc.x, 0.5f * acc.y, 0.5f * acc.z, 0.5f * acc.w};
    *(float4*)&aggm[(size_t)n * HID + lane * 4] = o;
  }
}

// ---------------- Layer 2: GEMM + fused logits ----------------
__launch_bounds__(256)
__global__ void k_gemm2(const float* __restrict__ aggm, const float* __restrict__ b1,
                        const float* __restrict__ W2, const float* __restrict__ as2,
                        const float* __restrict__ ad2, float* __restrict__ h2,
                        float* __restrict__ a_s, float* __restrict__ a_d, int N) {
  __shared__ float xs[16][HID];
  int tid = threadIdx.x;
  int row0 = blockIdx.x * 16;
  for (int t = tid; t < 16 * HID; t += 256) {
    int r = t >> 7, k = t & 127;
    int n = row0 + r;
    float v = 0.f;
    if (n < N) {
      v = aggm[(size_t)n * HID + k] + b1[k];
      v = (v > 0.f) ? v : 0.f;
    }
    xs[r][k] = v;
  }
  __syncthreads();
  int c = tid & 63, rs = tid >> 6;
  float acc[4] = {};
  for (int k = 0; k < HID; ++k) {
    float w = W2[(size_t)k * OUT_D + c];
    #pragma unroll
    for (int q = 0; q < 4; ++q) acc[q] += xs[rs + q * 4][k] * w;
  }
  float asv = as2[c], adv = ad2[c];
  #pragma unroll
  for (int q = 0; q < 4; ++q) {
    int n = row0 + rs + q * 4;
    if (n < N) h2[(size_t)n * OUT_D + c] = acc[q];
    float ps = acc[q] * asv, pd = acc[q] * adv;
    #pragma unroll
    for (int o = 32; o; o >>= 1) { ps += __shfl_xor(ps, o); pd += __shfl_xor(pd, o); }
    if (c == 0 && n < N) { a_s[n] = ps; a_d[n] = pd; }
  }
}

// ---------------- Layer 2: fused edge pipeline + bias -> out ----------------
__launch_bounds__(256)
__global__ void k_fagg2(const int* __restrict__ ro, const int* __restrict__ col,
                        const float* __restrict__ a_s, const float* __restrict__ a_d,
                        const float* __restrict__ h2, const float* __restrict__ b2,
                        float* __restrict__ out, int N) {
  int gid = blockIdx.x * blockDim.x + threadIdx.x;
  int n = gid >> 6, lane = gid & 63;
  if (n >= N) return;
  int beg = ro[n], end = ro[n + 1];
  float ad = a_d[n];

  float m = NEG_BIG, s = 0.f;
  for (int j = beg + lane; j < end; j += 64) {
    float v = lrelu(a_s[col[j]] + ad);
    float nm = fmaxf(m, v); s = s * __expf(m - nm) + __expf(v - nm); m = nm;
  }
  #pragma unroll
  for (int o = 32; o; o >>= 1) {
    float om = __shfl_xor(m, o), os = __shfl_xor(s, o);
    float nm = fmaxf(m, om);
    s = s * __expf(m - nm) + os * __expf(om - nm); m = nm;
  }
  float rcp = 1.f / s;
  float acc = 0.f;
  for (int j = beg; j < end; ++j) {
    int sidx = col[j];
    float v = lrelu(a_s[sidx] + ad);
    float al = __expf(v - m) * rcp;
    acc += al * h2[(size_t)sidx * OUT_D + lane];
  }
  out[(size_t)n * OUT_D + lane] = acc + b2[lane];
}

extern "C" void kernel_launch(void* const* d_in, const int* in_sizes, int n_in,
                              void* d_out, int out_size, void* d_ws, size_t ws_size,
                              hipStream_t stream) {
  const float* x    = (const float*)d_in[0];
  const int*   ei   = (const int*)d_in[1];    // harness converts int64 -> int32
  const float* W1   = (const float*)d_in[2];
  const float* as1w = (const float*)d_in[3];
  const float* ad1w = (const float*)d_in[4];
  const float* b1   = (const float*)d_in[5];
  const float* W2   = (const float*)d_in[6];
  const float* as2w = (const float*)d_in[7];
  const float* ad2w = (const float*)d_in[8];
  const float* b2   = (const float*)d_in[9];
  float* out = (float*)d_out;

  const int N  = in_sizes[0] / IN_D;
  const int E  = in_sizes[1] / 2;
  const int ET = E + N;
  const int NB = cdiv(N, SBS);

  // Workspace layout (element offsets in 4B units). ~140 MB.
  float* ws = (float*)d_ws;
  size_t off = 0;
  u16*   hb1  = (u16*)(ws + off); off += (size_t)N * IN_D / 2;  // bf16 h1
  float* h2   = ws + off; off += (size_t)N * OUT_D;
  float* aggm = ws + off; off += (size_t)N * HID;
  float* a_s1 = ws + off; off += (size_t)N * 2;
  float* a_d1 = ws + off; off += (size_t)N * 2;
  float* a_s2 = ws + off; off += N;
  float* a_d2 = ws + off; off += N;
  int*   deg  = (int*)(ws + off); off += N;
  int*   ro   = (int*)(ws + off); off += (size_t)N + 1;
  int*   cur  = (int*)(ws + off); off += N;
  int*   col  = (int*)(ws + off); off += ET;
  int*   bsum = (int*)(ws + off); off += 512;
  u16*   WThi = (u16*)(ws + off); off += (IN_D * IN_D) / 2;
  u16*   WTlo = (u16*)(ws + off); off += (IN_D * IN_D) / 2;

  // CSR build (group edges by dst; self-loops included via deg init = 1)
  k_initdeg<<<cdiv(N, 256), 256, 0, stream>>>(deg, N);
  k_hist<<<cdiv(E, 256), 256, 0, stream>>>(ei, E, deg);
  k_bsum<<<NB, SBS, 0, stream>>>(deg, bsum, N);
  k_bscan<<<1, 512, 0, stream>>>(bsum, NB, ro + N);
  k_bscan3<<<NB, SBS, 0, stream>>>(deg, bsum, ro, cur, N);
  k_scatter<<<cdiv(ET, 256), 256, 0, stream>>>(ei, E, ET, cur, col);

  // Layer 1
  k_prepW<<<cdiv(IN_D * IN_D, 256), 256, 0, stream>>>(W1, WThi, WTlo);
  k_gemm1<<<cdiv(N, 64), 256, 0, stream>>>(x, WThi, WTlo, as1w, ad1w, hb1, a_s1, a_d1, N);
  k_fagg1<<<cdiv((long long)N * 64, 256), 256, 0, stream>>>(ro, col, a_s1, a_d1, hb1, aggm, N);

  // Layer 2
  k_gemm2<<<cdiv(N, 16), 256, 0, stream>>>(aggm, b1, W2, as2w, ad2w, h2, a_s2, a_d2, N);
  k_fagg2<<<cdiv((long long)N * 64, 256), 256, 0, stream>>>(ro, col, a_s2, a_d2, h2, b2, out, N);
}

// Round 6
// 552.517 us; speedup vs baseline: 3.1811x; 1.2992x over previous
//
#include <hip/hip_runtime.h>
#include <hip/hip_bf16.h>
#include <cstdint>
#include <cstddef>

#define IN_D 256
#define HID 128
#define OUT_D 64
#define NSLOPE 0.2f
#define NEG_BIG -3.0e38f

typedef __attribute__((ext_vector_type(8))) short bf16x8;
typedef __attribute__((ext_vector_type(4))) float f32x4;
typedef __attribute__((ext_vector_type(8))) unsigned short u16x8;
typedef unsigned short u16;

static inline int cdiv(long long a, long long b) { return (int)((a + b - 1) / b); }

__device__ __forceinline__ void edge_sd(const int* __restrict__ ei, int E, int i,
                                        int& s, int& d) {
  if (i < E) { s = ei[i]; d = ei[E + i]; }
  else       { s = i - E; d = s; }
}

__device__ __forceinline__ float lrelu(float v) { return v >= 0.f ? v : NSLOPE * v; }

// f32 -> bf16 (RNE) via bit ops
__device__ __forceinline__ u16 f2bf(float f) {
  unsigned u = __float_as_uint(f);
  return (u16)((u + 0x7FFFu + ((u >> 16) & 1u)) >> 16);
}
__device__ __forceinline__ float bf2f(u16 h) {
  return __uint_as_float((unsigned)h << 16);
}

// ---------------- CSR build ----------------
__global__ void k_initdeg(int* deg, int N) {
  int i = blockIdx.x * blockDim.x + threadIdx.x;
  if (i < N) deg[i] = 1;  // self-loop
}

__global__ void k_hist(const int* __restrict__ ei, int E, int* __restrict__ deg) {
  int i = blockIdx.x * blockDim.x + threadIdx.x;
  if (i < E) atomicAdd(&deg[ei[E + i]], 1);
}

#define SBS 256
__global__ void k_bsum(const int* __restrict__ deg, int* __restrict__ bsum, int N) {
  int i = blockIdx.x * SBS + threadIdx.x;
  int v = (i < N) ? deg[i] : 0;
  #pragma unroll
  for (int o = 32; o; o >>= 1) v += __shfl_xor(v, o);
  __shared__ int sh[4];
  if ((threadIdx.x & 63) == 0) sh[threadIdx.x >> 6] = v;
  __syncthreads();
  if (threadIdx.x == 0) bsum[blockIdx.x] = sh[0] + sh[1] + sh[2] + sh[3];
}

__global__ void k_bscan(int* __restrict__ bsum, int NB, int* __restrict__ roN) {
  __shared__ int sh[512];
  int t = threadIdx.x;
  int v = (t < NB) ? bsum[t] : 0;
  sh[t] = v; __syncthreads();
  for (int o = 1; o < 512; o <<= 1) {
    int add = (t >= o) ? sh[t - o] : 0;
    __syncthreads();
    sh[t] += add;
    __syncthreads();
  }
  if (t < NB) bsum[t] = sh[t] - v;   // exclusive
  if (t == 511) *roN = sh[511];      // total = ET
}

__global__ void k_bscan3(const int* __restrict__ deg, const int* __restrict__ bsum,
                         int* __restrict__ ro, int* __restrict__ cur, int N) {
  int i = blockIdx.x * SBS + threadIdx.x;
  int v = (i < N) ? deg[i] : 0;
  __shared__ int sh[SBS];
  sh[threadIdx.x] = v; __syncthreads();
  for (int o = 1; o < SBS; o <<= 1) {
    int add = (threadIdx.x >= o) ? sh[threadIdx.x - o] : 0;
    __syncthreads();
    sh[threadIdx.x] += add;
    __syncthreads();
  }
  if (i < N) {
    int r = sh[threadIdx.x] - v + bsum[blockIdx.x];
    ro[i] = r; cur[i] = r;
  }
}

__global__ void k_scatter(const int* __restrict__ ei, int E, int ET,
                          int* __restrict__ cur, int* __restrict__ col) {
  int i = blockIdx.x * blockDim.x + threadIdx.x;
  if (i >= ET) return;
  int s, d; edge_sd(ei, E, i, s, d);
  int pos = atomicAdd(&cur[d], 1);
  col[pos] = s;
}

// ---------------- W1 prep: transpose + split to bf16 hi/lo -----------------
__global__ void k_prepW(const float* __restrict__ W, u16* __restrict__ WThi,
                        u16* __restrict__ WTlo) {
  int idx = blockIdx.x * 256 + threadIdx.x;
  if (idx >= IN_D * IN_D) return;
  int k = idx >> 8, n = idx & 255;
  float f = W[idx];
  u16 h = f2bf(f);
  u16 lo = f2bf(f - bf2f(h));
  WThi[n * IN_D + k] = h;
  WTlo[n * IN_D + k] = lo;
}

// ---------------- Layer 1: MFMA GEMM (split-bf16), LDS-staged B -------------
__launch_bounds__(256)
__global__ void k_gemm1(const float* __restrict__ x, const u16* __restrict__ WThi,
                        const u16* __restrict__ WTlo,
                        const float* __restrict__ as1, const float* __restrict__ ad1,
                        u16* __restrict__ hb, float* __restrict__ a_s,
                        float* __restrict__ a_d, int N) {
  __shared__ u16 ldsb[2][8192];  // [hi/lo][256 rows x 4 slots x 8 bf16] = 32KB
  int tid = threadIdx.x;
  int w = tid >> 6, l = tid & 63;
  int l15 = l & 15, l4 = l >> 4;
  int rowbase = blockIdx.x * 64 + w * 16;
  int row = rowbase + l15;
  int rowc = (row < N) ? row : (N - 1);
  const float* xp = x + (size_t)rowc * IN_D + l4 * 8;

  f32x4 acc[16];
  #pragma unroll
  for (int t = 0; t < 16; ++t) acc[t] = (f32x4){0.f, 0.f, 0.f, 0.f};

  const int ridx = (l15 * 4 + (l4 ^ (l15 & 3))) * 8;

  for (int kk = 0; kk < 8; ++kk) {
    __syncthreads();
    #pragma unroll
    for (int it = 0; it < 4; ++it) {
      int c = tid + it * 256;
      int n = c >> 2, ch = c & 3;
      size_t soff = (size_t)n * IN_D + kk * 32 + ch * 8;
      uint4 vh = *(const uint4*)(WThi + soff);
      uint4 vl = *(const uint4*)(WTlo + soff);
      int dsl = (n * 4 + (ch ^ (n & 3))) * 8;
      *(uint4*)&ldsb[0][dsl] = vh;
      *(uint4*)&ldsb[1][dsl] = vl;
    }
    __syncthreads();

    f32x4 v0 = *(const f32x4*)(xp + kk * 32);
    f32x4 v1 = *(const f32x4*)(xp + kk * 32 + 4);
    bf16x8 ah, al;
    #pragma unroll
    for (int j = 0; j < 4; ++j) {
      u16 h0 = f2bf(v0[j]);
      ah[j] = (short)h0; al[j] = (short)f2bf(v0[j] - bf2f(h0));
      u16 h1 = f2bf(v1[j]);
      ah[j + 4] = (short)h1; al[j + 4] = (short)f2bf(v1[j] - bf2f(h1));
    }
    #pragma unroll
    for (int t = 0; t < 16; ++t) {
      bf16x8 bh = *(const bf16x8*)&ldsb[0][ridx + t * 512];
      bf16x8 bl = *(const bf16x8*)&ldsb[1][ridx + t * 512];
      acc[t] = __builtin_amdgcn_mfma_f32_16x16x32_bf16(ah, bh, acc[t], 0, 0, 0);
      acc[t] = __builtin_amdgcn_mfma_f32_16x16x32_bf16(al, bh, acc[t], 0, 0, 0);
      acc[t] = __builtin_amdgcn_mfma_f32_16x16x32_bf16(ah, bl, acc[t], 0, 0, 0);
    }
  }

  #pragma unroll
  for (int r = 0; r < 4; ++r) {
    int rr = rowbase + l4 * 4 + r;
    if (rr < N) {
      u16* hp = hb + (size_t)rr * IN_D + l15;
      #pragma unroll
      for (int t = 0; t < 16; ++t) hp[t * 16] = f2bf(acc[t][r]);
    }
  }
  float asv[16], adv[16];
  #pragma unroll
  for (int t = 0; t < 16; ++t) { asv[t] = as1[t * 16 + l15]; adv[t] = ad1[t * 16 + l15]; }
  float ps0[4] = {}, ps1[4] = {}, pd0[4] = {}, pd1[4] = {};
  #pragma unroll
  for (int t = 0; t < 16; ++t) {
    #pragma unroll
    for (int r = 0; r < 4; ++r) {
      float v = acc[t][r];
      if (t < 8) { ps0[r] += v * asv[t]; pd0[r] += v * adv[t]; }
      else       { ps1[r] += v * asv[t]; pd1[r] += v * adv[t]; }
    }
  }
  #pragma unroll
  for (int r = 0; r < 4; ++r) {
    #pragma unroll
    for (int o = 1; o < 16; o <<= 1) {
      ps0[r] += __shfl_xor(ps0[r], o); ps1[r] += __shfl_xor(ps1[r], o);
      pd0[r] += __shfl_xor(pd0[r], o); pd1[r] += __shfl_xor(pd1[r], o);
    }
    int rr = rowbase + l4 * 4 + r;
    if (l15 == 0 && rr < N) {
      a_s[rr * 2] = ps0[r]; a_s[rr * 2 + 1] = ps1[r];
      a_d[rr * 2] = pd0[r]; a_d[rr * 2 + 1] = pd1[r];
    }
  }
}

// ---------------- Layer 1: fused edge pipeline (one wave per dst node) ------
// pass2: 2 edges/iter, 32-lane group per edge, ushort8 (16B) gathers
__launch_bounds__(256)
__global__ void k_fagg1(const int* __restrict__ ro, const int* __restrict__ col,
                        const float* __restrict__ a_s, const float* __restrict__ a_d,
                        const u16* __restrict__ hb, float* __restrict__ aggm, int N) {
  int gid = blockIdx.x * blockDim.x + threadIdx.x;
  int n = gid >> 6, lane = gid & 63;
  if (n >= N) return;
  int beg = ro[n], end = ro[n + 1];
  float ad0 = a_d[2 * n], ad1 = a_d[2 * n + 1];

  // pass 1: online softmax per head (lane-strided + wave merge)
  float m0 = NEG_BIG, s0 = 0.f, m1 = NEG_BIG, s1 = 0.f;
  for (int j = beg + lane; j < end; j += 64) {
    int sidx = col[j];
    float2 asv = *(const float2*)&a_s[2 * sidx];
    float v0 = lrelu(asv.x + ad0);
    float v1 = lrelu(asv.y + ad1);
    float nm0 = fmaxf(m0, v0); s0 = s0 * __expf(m0 - nm0) + __expf(v0 - nm0); m0 = nm0;
    float nm1 = fmaxf(m1, v1); s1 = s1 * __expf(m1 - nm1) + __expf(v1 - nm1); m1 = nm1;
  }
  #pragma unroll
  for (int o = 32; o; o >>= 1) {
    float om0 = __shfl_xor(m0, o), os0 = __shfl_xor(s0, o);
    float nm0 = fmaxf(m0, om0);
    s0 = s0 * __expf(m0 - nm0) + os0 * __expf(om0 - nm0); m0 = nm0;
    float om1 = __shfl_xor(m1, o), os1 = __shfl_xor(s1, o);
    float nm1 = fmaxf(m1, om1);
    s1 = s1 * __expf(m1 - nm1) + os1 * __expf(om1 - nm1); m1 = nm1;
  }
  float rcp0 = 1.f / s0, rcp1 = 1.f / s1;

  // pass 2: lanes 0-31 edge j, lanes 32-63 edge j+1; lane covers 8 channels
  int half = lane >> 5;
  int l5 = lane & 31;
  int head = l5 >> 4;          // 0-15: head0 ch, 16-31: head1 ch
  float myM = head ? m1 : m0;
  float myRcp = head ? rcp1 : rcp0;
  float myAd = head ? ad1 : ad0;
  float accv[8] = {};
  for (int j = beg; j < end; j += 2) {
    int jj = j + half;
    bool valid = jj < end;
    int sidx = col[valid ? jj : beg];
    float v = lrelu(a_s[2 * sidx + head] + myAd);
    float al = valid ? __expf(v - myM) * myRcp : 0.f;
    const u16x8 hv = *(const u16x8*)&hb[(size_t)sidx * IN_D + l5 * 8];
    #pragma unroll
    for (int q = 0; q < 8; ++q) accv[q] += al * bf2f(hv[q]);
  }
  // combine heads (xor 16), then edge-halves (xor 32); mean = *0.5
  #pragma unroll
  for (int q = 0; q < 8; ++q) {
    accv[q] += __shfl_xor(accv[q], 16);
    accv[q] += __shfl_xor(accv[q], 32);
    accv[q] *= 0.5f;
  }
  if (lane < 16) {
    float4 o0 = {accv[0], accv[1], accv[2], accv[3]};
    float4 o1 = {accv[4], accv[5], accv[6], accv[7]};
    *(float4*)&aggm[(size_t)n * HID + lane * 8] = o0;
    *(float4*)&aggm[(size_t)n * HID + lane * 8 + 4] = o1;
  }
}

// ---------------- Layer 2: GEMM + fused logits (h2 stored bf16) -------------
__launch_bounds__(256)
__global__ void k_gemm2(const float* __restrict__ aggm, const float* __restrict__ b1,
                        const float* __restrict__ W2, const float* __restrict__ as2,
                        const float* __restrict__ ad2, u16* __restrict__ h2b,
                        float* __restrict__ a_s, float* __restrict__ a_d, int N) {
  __shared__ float xs[16][HID];
  int tid = threadIdx.x;
  int row0 = blockIdx.x * 16;
  for (int t = tid; t < 16 * HID; t += 256) {
    int r = t >> 7, k = t & 127;
    int n = row0 + r;
    float v = 0.f;
    if (n < N) {
      v = aggm[(size_t)n * HID + k] + b1[k];
      v = (v > 0.f) ? v : 0.f;
    }
    xs[r][k] = v;
  }
  __syncthreads();
  int c = tid & 63, rs = tid >> 6;
  float acc[4] = {};
  for (int k = 0; k < HID; ++k) {
    float w = W2[(size_t)k * OUT_D + c];
    #pragma unroll
    for (int q = 0; q < 4; ++q) acc[q] += xs[rs + q * 4][k] * w;
  }
  float asv = as2[c], adv = ad2[c];
  #pragma unroll
  for (int q = 0; q < 4; ++q) {
    int n = row0 + rs + q * 4;
    if (n < N) h2b[(size_t)n * OUT_D + c] = f2bf(acc[q]);
    float ps = acc[q] * asv, pd = acc[q] * adv;
    #pragma unroll
    for (int o = 32; o; o >>= 1) { ps += __shfl_xor(ps, o); pd += __shfl_xor(pd, o); }
    if (c == 0 && n < N) { a_s[n] = ps; a_d[n] = pd; }
  }
}

// ---------------- Layer 2: fused edge pipeline + bias -> out ----------------
// pass2: 8 edges/iter, 8-lane group per edge, ushort8 (16B) gathers
__launch_bounds__(256)
__global__ void k_fagg2(const int* __restrict__ ro, const int* __restrict__ col,
                        const float* __restrict__ a_s, const float* __restrict__ a_d,
                        const u16* __restrict__ h2b, const float* __restrict__ b2,
                        float* __restrict__ out, int N) {
  int gid = blockIdx.x * blockDim.x + threadIdx.x;
  int n = gid >> 6, lane = gid & 63;
  if (n >= N) return;
  int beg = ro[n], end = ro[n + 1];
  float ad = a_d[n];

  float m = NEG_BIG, s = 0.f;
  for (int j = beg + lane; j < end; j += 64) {
    float v = lrelu(a_s[col[j]] + ad);
    float nm = fmaxf(m, v); s = s * __expf(m - nm) + __expf(v - nm); m = nm;
  }
  #pragma unroll
  for (int o = 32; o; o >>= 1) {
    float om = __shfl_xor(m, o), os = __shfl_xor(s, o);
    float nm = fmaxf(m, om);
    s = s * __expf(m - nm) + os * __expf(om - nm); m = nm;
  }
  float rcp = 1.f / s;

  int g = lane >> 3, l3 = lane & 7;
  float accv[8] = {};
  for (int j = beg; j < end; j += 8) {
    int jj = j + g;
    bool valid = jj < end;
    int sidx = col[valid ? jj : beg];
    float v = lrelu(a_s[sidx] + ad);
    float al = valid ? __expf(v - m) * rcp : 0.f;
    const u16x8 hv = *(const u16x8*)&h2b[(size_t)sidx * OUT_D + l3 * 8];
    #pragma unroll
    for (int q = 0; q < 8; ++q) accv[q] += al * bf2f(hv[q]);
  }
  #pragma unroll
  for (int q = 0; q < 8; ++q) {
    accv[q] += __shfl_xor(accv[q], 8);
    accv[q] += __shfl_xor(accv[q], 16);
    accv[q] += __shfl_xor(accv[q], 32);
  }
  if (lane < 8) {
    float* op = out + (size_t)n * OUT_D + lane * 8;
    const float* bp = b2 + lane * 8;
    float4 o0 = {accv[0] + bp[0], accv[1] + bp[1], accv[2] + bp[2], accv[3] + bp[3]};
    float4 o1 = {accv[4] + bp[4], accv[5] + bp[5], accv[6] + bp[6], accv[7] + bp[7]};
    *(float4*)op = o0;
    *(float4*)(op + 4) = o1;
  }
}

extern "C" void kernel_launch(void* const* d_in, const int* in_sizes, int n_in,
                              void* d_out, int out_size, void* d_ws, size_t ws_size,
                              hipStream_t stream) {
  const float* x    = (const float*)d_in[0];
  const int*   ei   = (const int*)d_in[1];
  const float* W1   = (const float*)d_in[2];
  const float* as1w = (const float*)d_in[3];
  const float* ad1w = (const float*)d_in[4];
  const float* b1   = (const float*)d_in[5];
  const float* W2   = (const float*)d_in[6];
  const float* as2w = (const float*)d_in[7];
  const float* ad2w = (const float*)d_in[8];
  const float* b2   = (const float*)d_in[9];
  float* out = (float*)d_out;

  const int N  = in_sizes[0] / IN_D;
  const int E  = in_sizes[1] / 2;
  const int ET = E + N;
  const int NB = cdiv(N, SBS);

  // Workspace layout (element offsets in 4B units). ~130 MB.
  float* ws = (float*)d_ws;
  size_t off = 0;
  u16*   hb1  = (u16*)(ws + off); off += (size_t)N * IN_D / 2;  // bf16 h1
  u16*   h2b  = (u16*)(ws + off); off += (size_t)N * OUT_D / 2; // bf16 h2
  float* aggm = ws + off; off += (size_t)N * HID;
  float* a_s1 = ws + off; off += (size_t)N * 2;
  float* a_d1 = ws + off; off += (size_t)N * 2;
  float* a_s2 = ws + off; off += N;
  float* a_d2 = ws + off; off += N;
  int*   deg  = (int*)(ws + off); off += N;
  int*   ro   = (int*)(ws + off); off += (size_t)N + 1;
  int*   cur  = (int*)(ws + off); off += N;
  int*   col  = (int*)(ws + off); off += ET;
  int*   bsum = (int*)(ws + off); off += 512;
  u16*   WThi = (u16*)(ws + off); off += (IN_D * IN_D) / 2;
  u16*   WTlo = (u16*)(ws + off); off += (IN_D * IN_D) / 2;

  // CSR build
  k_initdeg<<<cdiv(N, 256), 256, 0, stream>>>(deg, N);
  k_hist<<<cdiv(E, 256), 256, 0, stream>>>(ei, E, deg);
  k_bsum<<<NB, SBS, 0, stream>>>(deg, bsum, N);
  k_bscan<<<1, 512, 0, stream>>>(bsum, NB, ro + N);
  k_bscan3<<<NB, SBS, 0, stream>>>(deg, bsum, ro, cur, N);
  k_scatter<<<cdiv(ET, 256), 256, 0, stream>>>(ei, E, ET, cur, col);

  // Layer 1
  k_prepW<<<cdiv(IN_D * IN_D, 256), 256, 0, stream>>>(W1, WThi, WTlo);
  k_gemm1<<<cdiv(N, 64), 256, 0, stream>>>(x, WThi, WTlo, as1w, ad1w, hb1, a_s1, a_d1, N);
  k_fagg1<<<cdiv((long long)N * 64, 256), 256, 0, stream>>>(ro, col, a_s1, a_d1, hb1, aggm, N);

  // Layer 2
  k_gemm2<<<cdiv(N, 16), 256, 0, stream>>>(aggm, b1, W2, as2w, ad2w, h2b, a_s2, a_d2, N);
  k_fagg2<<<cdiv((long long)N * 64, 256), 256, 0, stream>>>(ro, col, a_s2, a_d2, h2b, b2, out, N);
}

// Round 7
// 539.365 us; speedup vs baseline: 3.2586x; 1.0244x over previous
//
#include <hip/hip_runtime.h>
#include <hip/hip_bf16.h>
#include <cstdint>
#include <cstddef>

#define IN_D 256
#define HID 128
#define OUT_D 64
#define NSLOPE 0.2f

typedef __attribute__((ext_vector_type(8))) short bf16x8;
typedef __attribute__((ext_vector_type(4))) float f32x4;
typedef __attribute__((ext_vector_type(8))) unsigned short u16x8;
typedef unsigned short u16;

static inline int cdiv(long long a, long long b) { return (int)((a + b - 1) / b); }

__device__ __forceinline__ void edge_sd(const int* __restrict__ ei, int E, int i,
                                        int& s, int& d) {
  if (i < E) { s = ei[i]; d = ei[E + i]; }
  else       { s = i - E; d = s; }
}

__device__ __forceinline__ float lrelu(float v) { return v >= 0.f ? v : NSLOPE * v; }

// f32 -> bf16 (RNE) via bit ops
__device__ __forceinline__ u16 f2bf(float f) {
  unsigned u = __float_as_uint(f);
  return (u16)((u + 0x7FFFu + ((u >> 16) & 1u)) >> 16);
}
__device__ __forceinline__ float bf2f(u16 h) {
  return __uint_as_float((unsigned)h << 16);
}

// ---------------- CSR build ----------------
__global__ void k_initdeg(int* deg, int N) {
  int i = blockIdx.x * blockDim.x + threadIdx.x;
  if (i < N) deg[i] = 1;  // self-loop
}

__global__ void k_hist(const int* __restrict__ ei, int E, int* __restrict__ deg) {
  int i = blockIdx.x * blockDim.x + threadIdx.x;
  if (i < E) atomicAdd(&deg[ei[E + i]], 1);
}

#define SBS 256
__global__ void k_bsum(const int* __restrict__ deg, int* __restrict__ bsum, int N) {
  int i = blockIdx.x * SBS + threadIdx.x;
  int v = (i < N) ? deg[i] : 0;
  #pragma unroll
  for (int o = 32; o; o >>= 1) v += __shfl_xor(v, o);
  __shared__ int sh[4];
  if ((threadIdx.x & 63) == 0) sh[threadIdx.x >> 6] = v;
  __syncthreads();
  if (threadIdx.x == 0) bsum[blockIdx.x] = sh[0] + sh[1] + sh[2] + sh[3];
}

__global__ void k_bscan(int* __restrict__ bsum, int NB, int* __restrict__ roN) {
  __shared__ int sh[512];
  int t = threadIdx.x;
  int v = (t < NB) ? bsum[t] : 0;
  sh[t] = v; __syncthreads();
  for (int o = 1; o < 512; o <<= 1) {
    int add = (t >= o) ? sh[t - o] : 0;
    __syncthreads();
    sh[t] += add;
    __syncthreads();
  }
  if (t < NB) bsum[t] = sh[t] - v;   // exclusive
  if (t == 511) *roN = sh[511];      // total = ET
}

__global__ void k_bscan3(const int* __restrict__ deg, const int* __restrict__ bsum,
                         int* __restrict__ ro, int* __restrict__ cur, int N) {
  int i = blockIdx.x * SBS + threadIdx.x;
  int v = (i < N) ? deg[i] : 0;
  __shared__ int sh[SBS];
  sh[threadIdx.x] = v; __syncthreads();
  for (int o = 1; o < SBS; o <<= 1) {
    int add = (threadIdx.x >= o) ? sh[threadIdx.x - o] : 0;
    __syncthreads();
    sh[threadIdx.x] += add;
    __syncthreads();
  }
  if (i < N) {
    int r = sh[threadIdx.x] - v + bsum[blockIdx.x];
    ro[i] = r; cur[i] = r;
  }
}

__global__ void k_scatter(const int* __restrict__ ei, int E, int ET,
                          int* __restrict__ cur, int* __restrict__ col) {
  int i = blockIdx.x * blockDim.x + threadIdx.x;
  if (i >= ET) return;
  int s, d; edge_sd(ei, E, i, s, d);
  int pos = atomicAdd(&cur[d], 1);
  col[pos] = s;
}

// ---------------- W1 prep: transpose + split to bf16 hi/lo -----------------
__global__ void k_prepW(const float* __restrict__ W, u16* __restrict__ WThi,
                        u16* __restrict__ WTlo) {
  int idx = blockIdx.x * 256 + threadIdx.x;
  if (idx >= IN_D * IN_D) return;
  int k = idx >> 8, n = idx & 255;
  float f = W[idx];
  u16 h = f2bf(f);
  u16 lo = f2bf(f - bf2f(h));
  WThi[n * IN_D + k] = h;
  WTlo[n * IN_D + k] = lo;
}

// ---------------- Layer 1: MFMA GEMM (split-bf16), LDS-staged B -------------
__launch_bounds__(256)
__global__ void k_gemm1(const float* __restrict__ x, const u16* __restrict__ WThi,
                        const u16* __restrict__ WTlo,
                        const float* __restrict__ as1, const float* __restrict__ ad1,
                        u16* __restrict__ hb, float* __restrict__ a_s,
                        float* __restrict__ a_d, int N) {
  __shared__ u16 ldsb[2][8192];  // [hi/lo][256 rows x 4 slots x 8 bf16] = 32KB
  int tid = threadIdx.x;
  int w = tid >> 6, l = tid & 63;
  int l15 = l & 15, l4 = l >> 4;
  int rowbase = blockIdx.x * 64 + w * 16;
  int row = rowbase + l15;
  int rowc = (row < N) ? row : (N - 1);
  const float* xp = x + (size_t)rowc * IN_D + l4 * 8;

  f32x4 acc[16];
  #pragma unroll
  for (int t = 0; t < 16; ++t) acc[t] = (f32x4){0.f, 0.f, 0.f, 0.f};

  const int ridx = (l15 * 4 + (l4 ^ (l15 & 3))) * 8;

  for (int kk = 0; kk < 8; ++kk) {
    __syncthreads();
    #pragma unroll
    for (int it = 0; it < 4; ++it) {
      int c = tid + it * 256;
      int n = c >> 2, ch = c & 3;
      size_t soff = (size_t)n * IN_D + kk * 32 + ch * 8;
      uint4 vh = *(const uint4*)(WThi + soff);
      uint4 vl = *(const uint4*)(WTlo + soff);
      int dsl = (n * 4 + (ch ^ (n & 3))) * 8;
      *(uint4*)&ldsb[0][dsl] = vh;
      *(uint4*)&ldsb[1][dsl] = vl;
    }
    __syncthreads();

    f32x4 v0 = *(const f32x4*)(xp + kk * 32);
    f32x4 v1 = *(const f32x4*)(xp + kk * 32 + 4);
    bf16x8 ah, al;
    #pragma unroll
    for (int j = 0; j < 4; ++j) {
      u16 h0 = f2bf(v0[j]);
      ah[j] = (short)h0; al[j] = (short)f2bf(v0[j] - bf2f(h0));
      u16 h1 = f2bf(v1[j]);
      ah[j + 4] = (short)h1; al[j + 4] = (short)f2bf(v1[j] - bf2f(h1));
    }
    #pragma unroll
    for (int t = 0; t < 16; ++t) {
      bf16x8 bh = *(const bf16x8*)&ldsb[0][ridx + t * 512];
      bf16x8 bl = *(const bf16x8*)&ldsb[1][ridx + t * 512];
      acc[t] = __builtin_amdgcn_mfma_f32_16x16x32_bf16(ah, bh, acc[t], 0, 0, 0);
      acc[t] = __builtin_amdgcn_mfma_f32_16x16x32_bf16(al, bh, acc[t], 0, 0, 0);
      acc[t] = __builtin_amdgcn_mfma_f32_16x16x32_bf16(ah, bl, acc[t], 0, 0, 0);
    }
  }

  #pragma unroll
  for (int r = 0; r < 4; ++r) {
    int rr = rowbase + l4 * 4 + r;
    if (rr < N) {
      u16* hp = hb + (size_t)rr * IN_D + l15;
      #pragma unroll
      for (int t = 0; t < 16; ++t) hp[t * 16] = f2bf(acc[t][r]);
    }
  }
  float asv[16], adv[16];
  #pragma unroll
  for (int t = 0; t < 16; ++t) { asv[t] = as1[t * 16 + l15]; adv[t] = ad1[t * 16 + l15]; }
  float ps0[4] = {}, ps1[4] = {}, pd0[4] = {}, pd1[4] = {};
  #pragma unroll
  for (int t = 0; t < 16; ++t) {
    #pragma unroll
    for (int r = 0; r < 4; ++r) {
      float v = acc[t][r];
      if (t < 8) { ps0[r] += v * asv[t]; pd0[r] += v * adv[t]; }
      else       { ps1[r] += v * asv[t]; pd1[r] += v * adv[t]; }
    }
  }
  #pragma unroll
  for (int r = 0; r < 4; ++r) {
    #pragma unroll
    for (int o = 1; o < 16; o <<= 1) {
      ps0[r] += __shfl_xor(ps0[r], o); ps1[r] += __shfl_xor(ps1[r], o);
      pd0[r] += __shfl_xor(pd0[r], o); pd1[r] += __shfl_xor(pd1[r], o);
    }
    int rr = rowbase + l4 * 4 + r;
    if (l15 == 0 && rr < N) {
      a_s[rr * 2] = ps0[r]; a_s[rr * 2 + 1] = ps1[r];
      a_d[rr * 2] = pd0[r]; a_d[rr * 2 + 1] = pd1[r];
    }
  }
}

// ---------------- Layer 1: fused edge pipeline (one wave per dst node) ------
// No max-subtraction (logits bounded, exp f32-safe; softmax scale-invariant).
// pass1 computes and STORES w_j = exp(lrelu(e)); pass2 consumes by broadcast.
__launch_bounds__(256)
__global__ void k_fagg1(const int* __restrict__ ro, const int* __restrict__ col,
                        const float* __restrict__ a_s, const float* __restrict__ a_d,
                        const u16* __restrict__ hb, float* __restrict__ wbuf,
                        float* __restrict__ aggm, int N) {
  int gid = blockIdx.x * blockDim.x + threadIdx.x;
  int n = gid >> 6, lane = gid & 63;
  if (n >= N) return;
  int beg = ro[n], end = ro[n + 1];
  float ad0 = a_d[2 * n], ad1 = a_d[2 * n + 1];

  // pass 1: w = exp(lrelu(a_s+a_d)), accumulate denominators, store w
  float s0 = 0.f, s1 = 0.f;
  for (int j = beg + lane; j < end; j += 64) {
    int sidx = col[j];
    float2 asv = *(const float2*)&a_s[2 * sidx];
    float w0 = __expf(lrelu(asv.x + ad0));
    float w1 = __expf(lrelu(asv.y + ad1));
    s0 += w0; s1 += w1;
    float2 wv = {w0, w1};
    *(float2*)&wbuf[2 * (size_t)j] = wv;
  }
  #pragma unroll
  for (int o = 32; o; o >>= 1) { s0 += __shfl_xor(s0, o); s1 += __shfl_xor(s1, o); }

  // pass 2: lanes 0-31 edge j, 32-63 edge j+1; lane covers 8 channels
  int half = lane >> 5;
  int l5 = lane & 31;
  int head = l5 >> 4;
  float accv[8] = {};
  #pragma unroll 2
  for (int j = beg; j < end; j += 2) {
    int jj = j + half;
    bool valid = jj < end;
    int jc = valid ? jj : beg;
    int sidx = col[jc];
    float2 wv = *(const float2*)&wbuf[2 * (size_t)jc];
    float al = valid ? (head ? wv.y : wv.x) : 0.f;
    const u16x8 hv = *(const u16x8*)&hb[(size_t)sidx * IN_D + l5 * 8];
    #pragma unroll
    for (int q = 0; q < 8; ++q) accv[q] += al * bf2f(hv[q]);
  }
  // fold 1/denom and 0.5 head-mean, then combine heads (xor16), halves (xor32)
  float myScale = 0.5f / (head ? s1 : s0);
  #pragma unroll
  for (int q = 0; q < 8; ++q) {
    accv[q] *= myScale;
    accv[q] += __shfl_xor(accv[q], 16);
    accv[q] += __shfl_xor(accv[q], 32);
  }
  if (lane < 16) {
    float4 o0 = {accv[0], accv[1], accv[2], accv[3]};
    float4 o1 = {accv[4], accv[5], accv[6], accv[7]};
    *(float4*)&aggm[(size_t)n * HID + lane * 8] = o0;
    *(float4*)&aggm[(size_t)n * HID + lane * 8 + 4] = o1;
  }
}

// ---------------- Layer 2: GEMM + fused logits (h2 stored bf16) -------------
__launch_bounds__(256)
__global__ void k_gemm2(const float* __restrict__ aggm, const float* __restrict__ b1,
                        const float* __restrict__ W2, const float* __restrict__ as2,
                        const float* __restrict__ ad2, u16* __restrict__ h2b,
                        float* __restrict__ a_s, float* __restrict__ a_d, int N) {
  __shared__ float xs[16][HID];
  int tid = threadIdx.x;
  int row0 = blockIdx.x * 16;
  for (int t = tid; t < 16 * HID; t += 256) {
    int r = t >> 7, k = t & 127;
    int n = row0 + r;
    float v = 0.f;
    if (n < N) {
      v = aggm[(size_t)n * HID + k] + b1[k];
      v = (v > 0.f) ? v : 0.f;
    }
    xs[r][k] = v;
  }
  __syncthreads();
  int c = tid & 63, rs = tid >> 6;
  float acc[4] = {};
  for (int k = 0; k < HID; ++k) {
    float w = W2[(size_t)k * OUT_D + c];
    #pragma unroll
    for (int q = 0; q < 4; ++q) acc[q] += xs[rs + q * 4][k] * w;
  }
  float asv = as2[c], adv = ad2[c];
  #pragma unroll
  for (int q = 0; q < 4; ++q) {
    int n = row0 + rs + q * 4;
    if (n < N) h2b[(size_t)n * OUT_D + c] = f2bf(acc[q]);
    float ps = acc[q] * asv, pd = acc[q] * adv;
    #pragma unroll
    for (int o = 32; o; o >>= 1) { ps += __shfl_xor(ps, o); pd += __shfl_xor(pd, o); }
    if (c == 0 && n < N) { a_s[n] = ps; a_d[n] = pd; }
  }
}

// ---------------- Layer 2: fused edge pipeline + bias -> out ----------------
// Same w-precompute scheme; 8 edges/iter, 8-lane group per edge.
__launch_bounds__(256)
__global__ void k_fagg2(const int* __restrict__ ro, const int* __restrict__ col,
                        const float* __restrict__ a_s, const float* __restrict__ a_d,
                        const u16* __restrict__ h2b, const float* __restrict__ b2,
                        float* __restrict__ wbuf, float* __restrict__ out, int N) {
  int gid = blockIdx.x * blockDim.x + threadIdx.x;
  int n = gid >> 6, lane = gid & 63;
  if (n >= N) return;
  int beg = ro[n], end = ro[n + 1];
  float ad = a_d[n];

  float s = 0.f;
  for (int j = beg + lane; j < end; j += 64) {
    float wv = __expf(lrelu(a_s[col[j]] + ad));
    s += wv;
    wbuf[j] = wv;
  }
  #pragma unroll
  for (int o = 32; o; o >>= 1) s += __shfl_xor(s, o);
  float rcp = 1.f / s;

  int g = lane >> 3, l3 = lane & 7;
  float accv[8] = {};
  #pragma unroll 2
  for (int j = beg; j < end; j += 8) {
    int jj = j + g;
    bool valid = jj < end;
    int jc = valid ? jj : beg;
    int sidx = col[jc];
    float al = valid ? wbuf[jc] : 0.f;
    const u16x8 hv = *(const u16x8*)&h2b[(size_t)sidx * OUT_D + l3 * 8];
    #pragma unroll
    for (int q = 0; q < 8; ++q) accv[q] += al * bf2f(hv[q]);
  }
  #pragma unroll
  for (int q = 0; q < 8; ++q) {
    accv[q] *= rcp;
    accv[q] += __shfl_xor(accv[q], 8);
    accv[q] += __shfl_xor(accv[q], 16);
    accv[q] += __shfl_xor(accv[q], 32);
  }
  if (lane < 8) {
    float* op = out + (size_t)n * OUT_D + lane * 8;
    const float* bp = b2 + lane * 8;
    float4 o0 = {accv[0] + bp[0], accv[1] + bp[1], accv[2] + bp[2], accv[3] + bp[3]};
    float4 o1 = {accv[4] + bp[4], accv[5] + bp[5], accv[6] + bp[6], accv[7] + bp[7]};
    *(float4*)op = o0;
    *(float4*)(op + 4) = o1;
  }
}

extern "C" void kernel_launch(void* const* d_in, const int* in_sizes, int n_in,
                              void* d_out, int out_size, void* d_ws, size_t ws_size,
                              hipStream_t stream) {
  const float* x    = (const float*)d_in[0];
  const int*   ei   = (const int*)d_in[1];
  const float* W1   = (const float*)d_in[2];
  const float* as1w = (const float*)d_in[3];
  const float* ad1w = (const float*)d_in[4];
  const float* b1   = (const float*)d_in[5];
  const float* W2   = (const float*)d_in[6];
  const float* as2w = (const float*)d_in[7];
  const float* ad2w = (const float*)d_in[8];
  const float* b2   = (const float*)d_in[9];
  float* out = (float*)d_out;

  const int N  = in_sizes[0] / IN_D;
  const int E  = in_sizes[1] / 2;
  const int ET = E + N;
  const int NB = cdiv(N, SBS);

  // Workspace layout (element offsets in 4B units). ~145 MB.
  float* ws = (float*)d_ws;
  size_t off = 0;
  u16*   hb1  = (u16*)(ws + off); off += (size_t)N * IN_D / 2;  // bf16 h1
  u16*   h2b  = (u16*)(ws + off); off += (size_t)N * OUT_D / 2; // bf16 h2
  float* aggm = ws + off; off += (size_t)N * HID;
  float* wbuf = ws + off; off += (size_t)ET * 2;   // per-edge softmax numerators
  float* a_s1 = ws + off; off += (size_t)N * 2;
  float* a_d1 = ws + off; off += (size_t)N * 2;
  float* a_s2 = ws + off; off += N;
  float* a_d2 = ws + off; off += N;
  int*   deg  = (int*)(ws + off); off += N;
  int*   ro   = (int*)(ws + off); off += (size_t)N + 1;
  int*   cur  = (int*)(ws + off); off += N;
  int*   col  = (int*)(ws + off); off += ET;
  int*   bsum = (int*)(ws + off); off += 512;
  u16*   WThi = (u16*)(ws + off); off += (IN_D * IN_D) / 2;
  u16*   WTlo = (u16*)(ws + off); off += (IN_D * IN_D) / 2;

  // CSR build
  k_initdeg<<<cdiv(N, 256), 256, 0, stream>>>(deg, N);
  k_hist<<<cdiv(E, 256), 256, 0, stream>>>(ei, E, deg);
  k_bsum<<<NB, SBS, 0, stream>>>(deg, bsum, N);
  k_bscan<<<1, 512, 0, stream>>>(bsum, NB, ro + N);
  k_bscan3<<<NB, SBS, 0, stream>>>(deg, bsum, ro, cur, N);
  k_scatter<<<cdiv(ET, 256), 256, 0, stream>>>(ei, E, ET, cur, col);

  // Layer 1
  k_prepW<<<cdiv(IN_D * IN_D, 256), 256, 0, stream>>>(W1, WThi, WTlo);
  k_gemm1<<<cdiv(N, 64), 256, 0, stream>>>(x, WThi, WTlo, as1w, ad1w, hb1, a_s1, a_d1, N);
  k_fagg1<<<cdiv((long long)N * 64, 256), 256, 0, stream>>>(ro, col, a_s1, a_d1, hb1, wbuf, aggm, N);

  // Layer 2
  k_gemm2<<<cdiv(N, 16), 256, 0, stream>>>(aggm, b1, W2, as2w, ad2w, h2b, a_s2, a_d2, N);
  k_fagg2<<<cdiv((long long)N * 64, 256), 256, 0, stream>>>(ro, col, a_s2, a_d2, h2b, b2, wbuf, out, N);
}

// Round 8
// 519.652 us; speedup vs baseline: 3.3822x; 1.0379x over previous
//
#include <hip/hip_runtime.h>
#include <hip/hip_bf16.h>
#include <cstdint>
#include <cstddef>

#define IN_D 256
#define HID 128
#define OUT_D 64
#define NSLOPE 0.2f

typedef __attribute__((ext_vector_type(8))) short bf16x8;
typedef __attribute__((ext_vector_type(4))) float f32x4;
typedef __attribute__((ext_vector_type(8))) unsigned short u16x8;
typedef unsigned short u16;

static inline int cdiv(long long a, long long b) { return (int)((a + b - 1) / b); }

__device__ __forceinline__ void edge_sd(const int* __restrict__ ei, int E, int i,
                                        int& s, int& d) {
  if (i < E) { s = ei[i]; d = ei[E + i]; }
  else       { s = i - E; d = s; }
}

__device__ __forceinline__ float lrelu(float v) { return v >= 0.f ? v : NSLOPE * v; }

// f32 -> bf16 (RNE) via bit ops
__device__ __forceinline__ u16 f2bf(float f) {
  unsigned u = __float_as_uint(f);
  return (u16)((u + 0x7FFFu + ((u >> 16) & 1u)) >> 16);
}
__device__ __forceinline__ float bf2f(u16 h) {
  return __uint_as_float((unsigned)h << 16);
}

// ---------------- CSR build ----------------
__global__ void k_initdeg(int* deg, int N) {
  int i = blockIdx.x * blockDim.x + threadIdx.x;
  if (i < N) deg[i] = 1;  // self-loop
}

__global__ void k_hist(const int* __restrict__ ei, int E, int* __restrict__ deg) {
  int i = blockIdx.x * blockDim.x + threadIdx.x;
  if (i < E) atomicAdd(&deg[ei[E + i]], 1);
}

#define SBS 256
__global__ void k_bsum(const int* __restrict__ deg, int* __restrict__ bsum, int N) {
  int i = blockIdx.x * SBS + threadIdx.x;
  int v = (i < N) ? deg[i] : 0;
  #pragma unroll
  for (int o = 32; o; o >>= 1) v += __shfl_xor(v, o);
  __shared__ int sh[4];
  if ((threadIdx.x & 63) == 0) sh[threadIdx.x >> 6] = v;
  __syncthreads();
  if (threadIdx.x == 0) bsum[blockIdx.x] = sh[0] + sh[1] + sh[2] + sh[3];
}

__global__ void k_bscan(int* __restrict__ bsum, int NB, int* __restrict__ roN) {
  __shared__ int sh[512];
  int t = threadIdx.x;
  int v = (t < NB) ? bsum[t] : 0;
  sh[t] = v; __syncthreads();
  for (int o = 1; o < 512; o <<= 1) {
    int add = (t >= o) ? sh[t - o] : 0;
    __syncthreads();
    sh[t] += add;
    __syncthreads();
  }
  if (t < NB) bsum[t] = sh[t] - v;   // exclusive
  if (t == 511) *roN = sh[511];      // total = ET
}

__global__ void k_bscan3(const int* __restrict__ deg, const int* __restrict__ bsum,
                         int* __restrict__ ro, int* __restrict__ cur, int N) {
  int i = blockIdx.x * SBS + threadIdx.x;
  int v = (i < N) ? deg[i] : 0;
  __shared__ int sh[SBS];
  sh[threadIdx.x] = v; __syncthreads();
  for (int o = 1; o < SBS; o <<= 1) {
    int add = (threadIdx.x >= o) ? sh[threadIdx.x - o] : 0;
    __syncthreads();
    sh[threadIdx.x] += add;
    __syncthreads();
  }
  if (i < N) {
    int r = sh[threadIdx.x] - v + bsum[blockIdx.x];
    ro[i] = r; cur[i] = r;
  }
}

__global__ void k_scatter(const int* __restrict__ ei, int E, int ET,
                          int* __restrict__ cur, int* __restrict__ col) {
  int i = blockIdx.x * blockDim.x + threadIdx.x;
  if (i >= ET) return;
  int s, d; edge_sd(ei, E, i, s, d);
  int pos = atomicAdd(&cur[d], 1);
  col[pos] = s;
}

// ---------------- W1 prep: transpose + split to bf16 hi/lo -----------------
__global__ void k_prepW(const float* __restrict__ W, u16* __restrict__ WThi,
                        u16* __restrict__ WTlo) {
  int idx = blockIdx.x * 256 + threadIdx.x;
  if (idx >= IN_D * IN_D) return;
  int k = idx >> 8, n = idx & 255;
  float f = W[idx];
  u16 h = f2bf(f);
  u16 lo = f2bf(f - bf2f(h));
  WThi[n * IN_D + k] = h;
  WTlo[n * IN_D + k] = lo;
}

// W2 [K=128][N=64] -> W2T hi/lo [64][128]
__global__ void k_prepW2(const float* __restrict__ W, u16* __restrict__ WThi,
                         u16* __restrict__ WTlo) {
  int idx = blockIdx.x * 256 + threadIdx.x;
  if (idx >= HID * OUT_D) return;
  int k = idx >> 6, n = idx & 63;
  float f = W[idx];
  u16 h = f2bf(f);
  u16 lo = f2bf(f - bf2f(h));
  WThi[n * HID + k] = h;
  WTlo[n * HID + k] = lo;
}

// ---------------- Layer 1: MFMA GEMM (split-bf16), LDS-staged B -------------
// BM=128 rows (8 waves x 16), 512 threads.
__launch_bounds__(512)
__global__ void k_gemm1(const float* __restrict__ x, const u16* __restrict__ WThi,
                        const u16* __restrict__ WTlo,
                        const float* __restrict__ as1, const float* __restrict__ ad1,
                        u16* __restrict__ hb, float* __restrict__ a_s,
                        float* __restrict__ a_d, int N) {
  __shared__ u16 ldsb[2][8192];  // [hi/lo][256 rows x 4 slots x 8 bf16] = 32KB
  int tid = threadIdx.x;
  int w = tid >> 6, l = tid & 63;
  int l15 = l & 15, l4 = l >> 4;
  int rowbase = blockIdx.x * 128 + w * 16;
  int row = rowbase + l15;
  int rowc = (row < N) ? row : (N - 1);
  const float* xp = x + (size_t)rowc * IN_D + l4 * 8;

  f32x4 acc[16];
  #pragma unroll
  for (int t = 0; t < 16; ++t) acc[t] = (f32x4){0.f, 0.f, 0.f, 0.f};

  const int ridx = (l15 * 4 + (l4 ^ (l15 & 3))) * 8;

  for (int kk = 0; kk < 8; ++kk) {
    __syncthreads();
    #pragma unroll
    for (int it = 0; it < 2; ++it) {
      int c = tid + it * 512;          // c in [0,1024): row n = c>>2, chunk ch = c&3
      int n = c >> 2, ch = c & 3;
      size_t soff = (size_t)n * IN_D + kk * 32 + ch * 8;
      uint4 vh = *(const uint4*)(WThi + soff);
      uint4 vl = *(const uint4*)(WTlo + soff);
      int dsl = (n * 4 + (ch ^ (n & 3))) * 8;
      *(uint4*)&ldsb[0][dsl] = vh;
      *(uint4*)&ldsb[1][dsl] = vl;
    }
    __syncthreads();

    f32x4 v0 = *(const f32x4*)(xp + kk * 32);
    f32x4 v1 = *(const f32x4*)(xp + kk * 32 + 4);
    bf16x8 ah, al;
    #pragma unroll
    for (int j = 0; j < 4; ++j) {
      u16 h0 = f2bf(v0[j]);
      ah[j] = (short)h0; al[j] = (short)f2bf(v0[j] - bf2f(h0));
      u16 h1 = f2bf(v1[j]);
      ah[j + 4] = (short)h1; al[j + 4] = (short)f2bf(v1[j] - bf2f(h1));
    }
    #pragma unroll
    for (int t = 0; t < 16; ++t) {
      bf16x8 bh = *(const bf16x8*)&ldsb[0][ridx + t * 512];
      bf16x8 bl = *(const bf16x8*)&ldsb[1][ridx + t * 512];
      acc[t] = __builtin_amdgcn_mfma_f32_16x16x32_bf16(ah, bh, acc[t], 0, 0, 0);
      acc[t] = __builtin_amdgcn_mfma_f32_16x16x32_bf16(al, bh, acc[t], 0, 0, 0);
      acc[t] = __builtin_amdgcn_mfma_f32_16x16x32_bf16(ah, bl, acc[t], 0, 0, 0);
    }
  }

  #pragma unroll
  for (int r = 0; r < 4; ++r) {
    int rr = rowbase + l4 * 4 + r;
    if (rr < N) {
      u16* hp = hb + (size_t)rr * IN_D + l15;
      #pragma unroll
      for (int t = 0; t < 16; ++t) hp[t * 16] = f2bf(acc[t][r]);
    }
  }
  float asv[16], adv[16];
  #pragma unroll
  for (int t = 0; t < 16; ++t) { asv[t] = as1[t * 16 + l15]; adv[t] = ad1[t * 16 + l15]; }
  float ps0[4] = {}, ps1[4] = {}, pd0[4] = {}, pd1[4] = {};
  #pragma unroll
  for (int t = 0; t < 16; ++t) {
    #pragma unroll
    for (int r = 0; r < 4; ++r) {
      float v = acc[t][r];
      if (t < 8) { ps0[r] += v * asv[t]; pd0[r] += v * adv[t]; }
      else       { ps1[r] += v * asv[t]; pd1[r] += v * adv[t]; }
    }
  }
  #pragma unroll
  for (int r = 0; r < 4; ++r) {
    #pragma unroll
    for (int o = 1; o < 16; o <<= 1) {
      ps0[r] += __shfl_xor(ps0[r], o); ps1[r] += __shfl_xor(ps1[r], o);
      pd0[r] += __shfl_xor(pd0[r], o); pd1[r] += __shfl_xor(pd1[r], o);
    }
    int rr = rowbase + l4 * 4 + r;
    if (l15 == 0 && rr < N) {
      a_s[rr * 2] = ps0[r]; a_s[rr * 2 + 1] = ps1[r];
      a_d[rr * 2] = pd0[r]; a_d[rr * 2 + 1] = pd1[r];
    }
  }
}

// ---------------- Layer 1: fused edge pipeline (one wave per dst node) ------
__launch_bounds__(256)
__global__ void k_fagg1(const int* __restrict__ ro, const int* __restrict__ col,
                        const float* __restrict__ a_s, const float* __restrict__ a_d,
                        const u16* __restrict__ hb, float* __restrict__ wbuf,
                        float* __restrict__ aggm, int N) {
  int gid = blockIdx.x * blockDim.x + threadIdx.x;
  int n = gid >> 6, lane = gid & 63;
  if (n >= N) return;
  int beg = ro[n], end = ro[n + 1];
  float ad0 = a_d[2 * n], ad1 = a_d[2 * n + 1];

  // pass 1: w = exp(lrelu(a_s+a_d)), accumulate denominators, store w
  float s0 = 0.f, s1 = 0.f;
  for (int j = beg + lane; j < end; j += 64) {
    int sidx = col[j];
    float2 asv = *(const float2*)&a_s[2 * sidx];
    float w0 = __expf(lrelu(asv.x + ad0));
    float w1 = __expf(lrelu(asv.y + ad1));
    s0 += w0; s1 += w1;
    float2 wv = {w0, w1};
    *(float2*)&wbuf[2 * (size_t)j] = wv;
  }
  #pragma unroll
  for (int o = 32; o; o >>= 1) { s0 += __shfl_xor(s0, o); s1 += __shfl_xor(s1, o); }

  // pass 2: lanes 0-31 edge j, 32-63 edge j+1; lane covers 8 channels
  int half = lane >> 5;
  int l5 = lane & 31;
  int head = l5 >> 4;
  float accv[8] = {};
  #pragma unroll 4
  for (int j = beg; j < end; j += 2) {
    int jj = j + half;
    bool valid = jj < end;
    int jc = valid ? jj : beg;
    int sidx = col[jc];
    float2 wv = *(const float2*)&wbuf[2 * (size_t)jc];
    float al = valid ? (head ? wv.y : wv.x) : 0.f;
    const u16x8 hv = *(const u16x8*)&hb[(size_t)sidx * IN_D + l5 * 8];
    #pragma unroll
    for (int q = 0; q < 8; ++q) accv[q] += al * bf2f(hv[q]);
  }
  float myScale = 0.5f / (head ? s1 : s0);
  #pragma unroll
  for (int q = 0; q < 8; ++q) {
    accv[q] *= myScale;
    accv[q] += __shfl_xor(accv[q], 16);
    accv[q] += __shfl_xor(accv[q], 32);
  }
  if (lane < 16) {
    float4 o0 = {accv[0], accv[1], accv[2], accv[3]};
    float4 o1 = {accv[4], accv[5], accv[6], accv[7]};
    *(float4*)&aggm[(size_t)n * HID + lane * 8] = o0;
    *(float4*)&aggm[(size_t)n * HID + lane * 8 + 4] = o1;
  }
}

// ---------------- Layer 2: MFMA GEMM (split-bf16) + fused logits ------------
// A = relu(aggm + b1) built in-registers; B = W2T hi/lo (L2-resident, 32KB).
// Block = 4 waves x 16 rows = 64 rows; per wave: 4 kk x 4 t x 3 MFMA.
__launch_bounds__(256)
__global__ void k_gemm2(const float* __restrict__ aggm, const float* __restrict__ b1,
                        const u16* __restrict__ WThi, const u16* __restrict__ WTlo,
                        const float* __restrict__ as2, const float* __restrict__ ad2,
                        u16* __restrict__ h2b, float* __restrict__ a_s,
                        float* __restrict__ a_d, int N) {
  int tid = threadIdx.x;
  int w = tid >> 6, l = tid & 63;
  int l15 = l & 15, l4 = l >> 4;
  int rowbase = blockIdx.x * 64 + w * 16;
  int row = rowbase + l15;
  int rowc = (row < N) ? row : (N - 1);
  const float* ap = aggm + (size_t)rowc * HID + l4 * 8;
  const float* bp = b1 + l4 * 8;

  f32x4 acc[4];
  #pragma unroll
  for (int t = 0; t < 4; ++t) acc[t] = (f32x4){0.f, 0.f, 0.f, 0.f};

  #pragma unroll
  for (int kk = 0; kk < 4; ++kk) {
    f32x4 v0 = *(const f32x4*)(ap + kk * 32);
    f32x4 v1 = *(const f32x4*)(ap + kk * 32 + 4);
    f32x4 b0 = *(const f32x4*)(bp + kk * 32);
    f32x4 b1v = *(const f32x4*)(bp + kk * 32 + 4);
    bf16x8 ah, al;
    #pragma unroll
    for (int j = 0; j < 4; ++j) {
      float u0 = v0[j] + b0[j]; u0 = (u0 > 0.f) ? u0 : 0.f;
      u16 h0 = f2bf(u0);
      ah[j] = (short)h0; al[j] = (short)f2bf(u0 - bf2f(h0));
      float u1 = v1[j] + b1v[j]; u1 = (u1 > 0.f) ? u1 : 0.f;
      u16 h1 = f2bf(u1);
      ah[j + 4] = (short)h1; al[j + 4] = (short)f2bf(u1 - bf2f(h1));
    }
    size_t boff = (size_t)l15 * HID + kk * 32 + l4 * 8;
    #pragma unroll
    for (int t = 0; t < 4; ++t) {
      bf16x8 bh = *(const bf16x8*)(WThi + boff + (size_t)t * 16 * HID);
      bf16x8 bl = *(const bf16x8*)(WTlo + boff + (size_t)t * 16 * HID);
      acc[t] = __builtin_amdgcn_mfma_f32_16x16x32_bf16(ah, bh, acc[t], 0, 0, 0);
      acc[t] = __builtin_amdgcn_mfma_f32_16x16x32_bf16(al, bh, acc[t], 0, 0, 0);
      acc[t] = __builtin_amdgcn_mfma_f32_16x16x32_bf16(ah, bl, acc[t], 0, 0, 0);
    }
  }

  // store h2b (D layout: row = rowbase + l4*4 + r, col = t*16 + l15)
  #pragma unroll
  for (int r = 0; r < 4; ++r) {
    int rr = rowbase + l4 * 4 + r;
    if (rr < N) {
      u16* hp = h2b + (size_t)rr * OUT_D + l15;
      #pragma unroll
      for (int t = 0; t < 4; ++t) hp[t * 16] = f2bf(acc[t][r]);
    }
  }
  // fused logits over 64 cols
  float asv[4], adv[4];
  #pragma unroll
  for (int t = 0; t < 4; ++t) { asv[t] = as2[t * 16 + l15]; adv[t] = ad2[t * 16 + l15]; }
  #pragma unroll
  for (int r = 0; r < 4; ++r) {
    float ps = 0.f, pd = 0.f;
    #pragma unroll
    for (int t = 0; t < 4; ++t) { ps += acc[t][r] * asv[t]; pd += acc[t][r] * adv[t]; }
    #pragma unroll
    for (int o = 1; o < 16; o <<= 1) { ps += __shfl_xor(ps, o); pd += __shfl_xor(pd, o); }
    int rr = rowbase + l4 * 4 + r;
    if (l15 == 0 && rr < N) { a_s[rr] = ps; a_d[rr] = pd; }
  }
}

// ---------------- Layer 2: fused edge pipeline + bias -> out ----------------
__launch_bounds__(256)
__global__ void k_fagg2(const int* __restrict__ ro, const int* __restrict__ col,
                        const float* __restrict__ a_s, const float* __restrict__ a_d,
                        const u16* __restrict__ h2b, const float* __restrict__ b2,
                        float* __restrict__ wbuf, float* __restrict__ out, int N) {
  int gid = blockIdx.x * blockDim.x + threadIdx.x;
  int n = gid >> 6, lane = gid & 63;
  if (n >= N) return;
  int beg = ro[n], end = ro[n + 1];
  float ad = a_d[n];

  float s = 0.f;
  for (int j = beg + lane; j < end; j += 64) {
    float wv = __expf(lrelu(a_s[col[j]] + ad));
    s += wv;
    wbuf[j] = wv;
  }
  #pragma unroll
  for (int o = 32; o; o >>= 1) s += __shfl_xor(s, o);
  float rcp = 1.f / s;

  int g = lane >> 3, l3 = lane & 7;
  float accv[8] = {};
  #pragma unroll 4
  for (int j = beg; j < end; j += 8) {
    int jj = j + g;
    bool valid = jj < end;
    int jc = valid ? jj : beg;
    int sidx = col[jc];
    float al = valid ? wbuf[jc] : 0.f;
    const u16x8 hv = *(const u16x8*)&h2b[(size_t)sidx * OUT_D + l3 * 8];
    #pragma unroll
    for (int q = 0; q < 8; ++q) accv[q] += al * bf2f(hv[q]);
  }
  #pragma unroll
  for (int q = 0; q < 8; ++q) {
    accv[q] *= rcp;
    accv[q] += __shfl_xor(accv[q], 8);
    accv[q] += __shfl_xor(accv[q], 16);
    accv[q] += __shfl_xor(accv[q], 32);
  }
  if (lane < 8) {
    float* op = out + (size_t)n * OUT_D + lane * 8;
    const float* bp = b2 + lane * 8;
    float4 o0 = {accv[0] + bp[0], accv[1] + bp[1], accv[2] + bp[2], accv[3] + bp[3]};
    float4 o1 = {accv[4] + bp[4], accv[5] + bp[5], accv[6] + bp[6], accv[7] + bp[7]};
    *(float4*)op = o0;
    *(float4*)(op + 4) = o1;
  }
}

extern "C" void kernel_launch(void* const* d_in, const int* in_sizes, int n_in,
                              void* d_out, int out_size, void* d_ws, size_t ws_size,
                              hipStream_t stream) {
  const float* x    = (const float*)d_in[0];
  const int*   ei   = (const int*)d_in[1];
  const float* W1   = (const float*)d_in[2];
  const float* as1w = (const float*)d_in[3];
  const float* ad1w = (const float*)d_in[4];
  const float* b1   = (const float*)d_in[5];
  const float* W2   = (const float*)d_in[6];
  const float* as2w = (const float*)d_in[7];
  const float* ad2w = (const float*)d_in[8];
  const float* b2   = (const float*)d_in[9];
  float* out = (float*)d_out;

  const int N  = in_sizes[0] / IN_D;
  const int E  = in_sizes[1] / 2;
  const int ET = E + N;
  const int NB = cdiv(N, SBS);

  // Workspace layout (element offsets in 4B units). ~145 MB.
  float* ws = (float*)d_ws;
  size_t off = 0;
  u16*   hb1  = (u16*)(ws + off); off += (size_t)N * IN_D / 2;  // bf16 h1
  u16*   h2b  = (u16*)(ws + off); off += (size_t)N * OUT_D / 2; // bf16 h2
  float* aggm = ws + off; off += (size_t)N * HID;
  float* wbuf = ws + off; off += (size_t)ET * 2;   // per-edge softmax numerators
  float* a_s1 = ws + off; off += (size_t)N * 2;
  float* a_d1 = ws + off; off += (size_t)N * 2;
  float* a_s2 = ws + off; off += N;
  float* a_d2 = ws + off; off += N;
  int*   deg  = (int*)(ws + off); off += N;
  int*   ro   = (int*)(ws + off); off += (size_t)N + 1;
  int*   cur  = (int*)(ws + off); off += N;
  int*   col  = (int*)(ws + off); off += ET;
  int*   bsum = (int*)(ws + off); off += 512;
  u16*   WThi = (u16*)(ws + off); off += (IN_D * IN_D) / 2;
  u16*   WTlo = (u16*)(ws + off); off += (IN_D * IN_D) / 2;
  u16*   W2Thi = (u16*)(ws + off); off += (HID * OUT_D) / 2;
  u16*   W2Tlo = (u16*)(ws + off); off += (HID * OUT_D) / 2;

  // CSR build
  k_initdeg<<<cdiv(N, 256), 256, 0, stream>>>(deg, N);
  k_hist<<<cdiv(E, 256), 256, 0, stream>>>(ei, E, deg);
  k_bsum<<<NB, SBS, 0, stream>>>(deg, bsum, N);
  k_bscan<<<1, 512, 0, stream>>>(bsum, NB, ro + N);
  k_bscan3<<<NB, SBS, 0, stream>>>(deg, bsum, ro, cur, N);
  k_scatter<<<cdiv(ET, 256), 256, 0, stream>>>(ei, E, ET, cur, col);

  // Weight prep
  k_prepW<<<cdiv(IN_D * IN_D, 256), 256, 0, stream>>>(W1, WThi, WTlo);
  k_prepW2<<<cdiv(HID * OUT_D, 256), 256, 0, stream>>>(W2, W2Thi, W2Tlo);

  // Layer 1
  k_gemm1<<<cdiv(N, 128), 512, 0, stream>>>(x, WThi, WTlo, as1w, ad1w, hb1, a_s1, a_d1, N);
  k_fagg1<<<cdiv((long long)N * 64, 256), 256, 0, stream>>>(ro, col, a_s1, a_d1, hb1, wbuf, aggm, N);

  // Layer 2
  k_gemm2<<<cdiv(N, 64), 256, 0, stream>>>(aggm, b1, W2Thi, W2Tlo, as2w, ad2w, h2b, a_s2, a_d2, N);
  k_fagg2<<<cdiv((long long)N * 64, 256), 256, 0, stream>>>(ro, col, a_s2, a_d2, h2b, b2, wbuf, out, N);
}